// Round 5
// baseline (395.754 us; speedup 1.0000x reference)
//
#include <hip/hip_runtime.h>
#include <math.h>

// ---------------------------------------------------------------------------
// Sinkhorn ETP (FASTopic) on MI355X.
// n=256 topics, m=32768 words, D=384.
//
//   log_K0[i,j] = G[i,j] + su0[i] + sv0[j],  G = 40 * x@y^T
//   Per iteration:  W[j] = log_b - lse_i(G+su);  su'[i] = log_a - lse_j(G+W)
//   (su-state absorbs su0; sv0 absorbs into W — verified identity, R13 notes)
//   Final: transp[i,j] = exp(G+su[i]+W[j]); M = nx[i]+ny[j]-0.05*G;
//          loss = sum(transp*M)
//
// R8: E-reuse fast path (iters 2..100). R9-R12 (failed levers, productive
// post-mortems): VGPR cap, reg pin, structure clone, nt stores — sink_step
// stayed ~75us. R12's counters finally closed the mechanism: during the
// first reader's window FETCH=17MB at 240GB/s = 71us = the whole kernel.
// Half of G is L3-resident (fast), the HBM half reads at 3% of peak.
// Mechanism: the iteration kernels read G as a COLUMN SLAB - 256B contiguous
// per row at a 128KB power-of-2 stride -> DRAM channel/bank hash collapse.
// sink_fast/colerr are fast ONLY because G is L3-resident by their turn (the
// IC's slice hashing tolerates the pattern; DRAM's doesn't). init_k streams
// y row-major from HBM at full speed - same chip, friendly pattern.
//
// R13: make the first G read row-contiguous.
//   col_pass (256 blocks): block owns 128 cols x ALL 256 rows; per row reads
//     512B contiguous (wave = 2 rows x 1KB). W computed fully in-block.
//     Exact 2-pass lse (max, expsum), tile pinned in regs (~128 VGPR, 1
//     block/CU by design - BW-bound).
//   row_pass (512 blocks): old sink_step2 passes 3-4 + tree combine, W from
//     global. Second reader -> L3-hot -> sink_fast-class speed.
// Predicted: col_pass 4-10us (FETCH ~17MB at >=2TB/s, VALUBusy >25%),
// row_pass ~3us, total ~315-325us. Falsifier: col_pass ~70us -> stride
// theory dead -> R14 fuses column partials into gemm's epilogue (registers).
// ---------------------------------------------------------------------------

#define N_TOPIC 256
#define N_WORD  32768

static constexpr float LOG_A = -5.545177444479562f;    // log(1/256 + 1e-30)
static constexpr float LOG_B = -10.397207708399179f;   // log(1/32768 + 1e-30)
static constexpr float BVAL  = 3.0517578125e-05f;      // 1/32768

typedef float f32x4 __attribute__((ext_vector_type(4)));
typedef short bf16x8 __attribute__((ext_vector_type(8)));

// Keep a float4's lanes pinned in VGPRs: empty asm is an opaque use+def, so
// the compiler cannot re-materialize the global load that produced them.
#define PIN4(v) asm volatile("" : "+v"((v).x), "+v"((v).y), "+v"((v).z), "+v"((v).w))

// ---------------------------------------------------------------- init ------
__global__ __launch_bounds__(256) void init_k(
    const float* __restrict__ x, const float* __restrict__ y,
    float* __restrict__ nx, float* __restrict__ ny, float* __restrict__ su,
    unsigned* __restrict__ colerr, int* __restrict__ active,
    int* __restrict__ counters, float* __restrict__ out)
{
    const int b = blockIdx.x, t = threadIdx.x;
    const int w = t >> 6, l = t & 63;
    if (b < 8192) {                       // ||y_j||^2, 4 rows/block (wave per row)
        const int r = (b << 2) + w;
        const float4* y4 = (const float4*)y;
        float4 v = y4[r * 96 + l];
        float s = v.x * v.x + v.y * v.y + v.z * v.z + v.w * v.w;
        if (l < 32) {
            float4 u = y4[r * 96 + 64 + l];
            s += u.x * u.x + u.y * u.y + u.z * u.z + u.w * u.w;
        }
        for (int off = 32; off; off >>= 1) s += __shfl_down(s, off);
        if (l == 0) ny[r] = s;
    } else if (b < 8256) {                // ||x_i||^2 and su0 = -20*nx
        const int r = ((b - 8192) << 2) + w;
        const float4* x4 = (const float4*)x;
        float4 v = x4[r * 96 + l];
        float s = v.x * v.x + v.y * v.y + v.z * v.z + v.w * v.w;
        if (l < 32) {
            float4 u = x4[r * 96 + 64 + l];
            s += u.x * u.x + u.y * u.y + u.z * u.z + u.w * u.w;
        }
        for (int off = 32; off; off >>= 1) s += __shfl_down(s, off);
        if (l == 0) { nx[r] = s; su[r] = -20.f * s; }
    } else {
        for (int k = t; k < 4096; k += 256) counters[k] = 0;
        if (t == 0) { colerr[0] = 0u; colerr[1] = 0u; active[0] = 1; out[0] = 0.f; }
    }
}

// ---------------------------------------------------------------- gemm ------
// Exact 3-way bf16 truncation split: v = b0 + b1 + b2 (+ r3, |r3|<=2^-27|v|).
static __device__ __forceinline__ void split3(float v, ushort& h0, ushort& h1, ushort& h2)
{
    unsigned u0 = __float_as_uint(v);
    h0 = (ushort)(u0 >> 16);
    float r1 = v - __uint_as_float(u0 & 0xFFFF0000u);
    unsigned u1 = __float_as_uint(r1);
    h1 = (ushort)(u1 >> 16);
    float r2 = r1 - __uint_as_float(u1 & 0xFFFF0000u);
    h2 = (ushort)(__float_as_uint(r2) >> 16);
}

// Block tile 128i x 128j, K-chunks of 32, grid (256 jb, 2 ib) = 512 blocks.
// Frag layouts (m89/m91-verified); y is [j][k] row-major = B^T identical frag.
__global__ __launch_bounds__(256, 1) void gemm_k(
    const float* __restrict__ x, const float* __restrict__ y, float* __restrict__ G)
{
    __shared__ __align__(16) ushort xs0[5120], xs1[5120], xs2[5120];
    __shared__ __align__(16) ushort ys0[5120], ys1[5120], ys2[5120];

    const int t   = threadIdx.x;
    const int jb  = blockIdx.x << 7;   // 128-col slab
    const int ib  = blockIdx.y << 7;   // 128-row slab
    const int w   = t >> 6;            // wave 0..3
    const int ln  = t & 63;
    const int q   = ln >> 4;           // quad 0..3
    const int l15 = ln & 15;

    const float4* x4 = (const float4*)x;
    const float4* y4 = (const float4*)y;

    f32x4 acc[2][8];
#pragma unroll
    for (int mi = 0; mi < 2; ++mi)
#pragma unroll
        for (int nj = 0; nj < 8; ++nj) acc[mi][nj] = (f32x4){0.f, 0.f, 0.f, 0.f};

    for (int kc = 0; kc < 12; ++kc) {
        __syncthreads();
#pragma unroll
        for (int p = 0; p < 4; ++p) {
            const int f  = (t << 2) + p;       // 0..1023 float4 slots
            const int r  = f >> 3, c4 = f & 7; // row, k-quad
            const int o  = r * 40 + (c4 << 2);
            float4 vx = x4[(ib + r) * 96 + (kc << 3) + c4];
            ushort a0,a1,a2,b0,b1,b2,c0,c1,c2,d0,d1,d2;
            split3(vx.x, a0,a1,a2); split3(vx.y, b0,b1,b2);
            split3(vx.z, c0,c1,c2); split3(vx.w, d0,d1,d2);
            *(ushort4*)&xs0[o] = make_ushort4(a0,b0,c0,d0);
            *(ushort4*)&xs1[o] = make_ushort4(a1,b1,c1,d1);
            *(ushort4*)&xs2[o] = make_ushort4(a2,b2,c2,d2);
            float4 vy = y4[(jb + r) * 96 + (kc << 3) + c4];
            split3(vy.x, a0,a1,a2); split3(vy.y, b0,b1,b2);
            split3(vy.z, c0,c1,c2); split3(vy.w, d0,d1,d2);
            *(ushort4*)&ys0[o] = make_ushort4(a0,b0,c0,d0);
            *(ushort4*)&ys1[o] = make_ushort4(a1,b1,c1,d1);
            *(ushort4*)&ys2[o] = make_ushort4(a2,b2,c2,d2);
        }
        __syncthreads();

        bf16x8 A[3][2];
#pragma unroll
        for (int mi = 0; mi < 2; ++mi) {
            const int off = ((w << 5) + (mi << 4) + l15) * 40 + (q << 3);
            A[0][mi] = *(const bf16x8*)&xs0[off];
            A[1][mi] = *(const bf16x8*)&xs1[off];
            A[2][mi] = *(const bf16x8*)&xs2[off];
        }
#pragma unroll
        for (int nj = 0; nj < 8; ++nj) {
            const int off = ((nj << 4) + l15) * 40 + (q << 3);
            bf16x8 B0 = *(const bf16x8*)&ys0[off];
            bf16x8 B1 = *(const bf16x8*)&ys1[off];
            bf16x8 B2 = *(const bf16x8*)&ys2[off];
#pragma unroll
            for (int mi = 0; mi < 2; ++mi) {
                f32x4 c = acc[mi][nj];
                c = __builtin_amdgcn_mfma_f32_16x16x32_bf16(A[0][mi], B0, c, 0, 0, 0);
                c = __builtin_amdgcn_mfma_f32_16x16x32_bf16(A[0][mi], B1, c, 0, 0, 0);
                c = __builtin_amdgcn_mfma_f32_16x16x32_bf16(A[1][mi], B0, c, 0, 0, 0);
                c = __builtin_amdgcn_mfma_f32_16x16x32_bf16(A[1][mi], B1, c, 0, 0, 0);
                c = __builtin_amdgcn_mfma_f32_16x16x32_bf16(A[0][mi], B2, c, 0, 0, 0);
                c = __builtin_amdgcn_mfma_f32_16x16x32_bf16(A[2][mi], B0, c, 0, 0, 0);
                acc[mi][nj] = c;
            }
        }
    }
#pragma unroll
    for (int mi = 0; mi < 2; ++mi) {
        const int gi0 = ib + (w << 5) + (mi << 4) + (q << 2);
#pragma unroll
        for (int nj = 0; nj < 8; ++nj) {
            const int gj = jb + (nj << 4) + l15;
#pragma unroll
            for (int r = 0; r < 4; ++r)
                __builtin_nontemporal_store(40.f * acc[mi][nj][r],
                                            &G[(size_t)(gi0 + r) * 32768 + gj]);
        }
    }
}

// ------------------------------------- iteration 1, column pass (W) ---------
// R13: FIRST reader of G -> row-contiguous streaming. Block c owns cols
// [128c,128c+128) x all 256 rows; wave reads 2 rows x 512B contiguous per
// issue. W[j] = LOG_B - lse_i(G+su) computed fully in-block (exact 2-pass).
__global__ __launch_bounds__(256, 1) void col_pass(
    const float* __restrict__ G, const float* __restrict__ su,
    float* __restrict__ W)
{
    __shared__ float su_lds[256];
    __shared__ float mm[8 * 128];
    __shared__ float ss[8 * 128];

    const int t  = threadIdx.x;
    const int c  = blockIdx.x;         // 128-col chunk
    const int w  = t >> 6;             // wave 0..3
    const int l  = t & 63;
    const int l5 = l & 31;             // col-quad within chunk (cols 4*l5..+4)
    const int rb = l >> 5;             // row parity within pair

    su_lds[t] = su[t];
    __syncthreads();

    const float4* G4 = (const float4*)G;
    // rows visited by this thread: i = 8k + 2w + rb, k = 0..31  (all 256 rows
    // covered across w,rb). Per (row, wave): 64 lanes read 1KB contiguous
    // (lanes 0-31 row A, 32-63 row B -> 512B per row).
    float4 tile[32];
#pragma unroll
    for (int k = 0; k < 32; ++k) {
        const int i = (k << 3) + (w << 1) + rb;
        tile[k] = G4[i * 8192 + (c << 5) + l5];
    }
#pragma unroll
    for (int k = 0; k < 32; ++k) PIN4(tile[k]);

    // pass A: per-col max of (G+su) over this thread's 32 rows
    float m0 = -INFINITY, m1 = -INFINITY, m2 = -INFINITY, m3 = -INFINITY;
#pragma unroll
    for (int k = 0; k < 32; ++k) {
        const float sk = su_lds[(k << 3) + (w << 1) + rb];
        m0 = fmaxf(m0, tile[k].x + sk);
        m1 = fmaxf(m1, tile[k].y + sk);
        m2 = fmaxf(m2, tile[k].z + sk);
        m3 = fmaxf(m3, tile[k].w + sk);
    }
    // pass B: expsum vs per-thread max
    float s0 = 0.f, s1 = 0.f, s2 = 0.f, s3 = 0.f;
#pragma unroll
    for (int k = 0; k < 32; ++k) {
        const float sk = su_lds[(k << 3) + (w << 1) + rb];
        s0 += __expf(tile[k].x + sk - m0);
        s1 += __expf(tile[k].y + sk - m1);
        s2 += __expf(tile[k].z + sk - m2);
        s3 += __expf(tile[k].w + sk - m3);
    }
    // deposit 8 partials per column (p = 2w+rb), cols 4*l5..4*l5+3
    const int p = (w << 1) + rb;
    const int c0 = l5 << 2;
    mm[p * 128 + c0 + 0] = m0; ss[p * 128 + c0 + 0] = s0;
    mm[p * 128 + c0 + 1] = m1; ss[p * 128 + c0 + 1] = s1;
    mm[p * 128 + c0 + 2] = m2; ss[p * 128 + c0 + 2] = s2;
    mm[p * 128 + c0 + 3] = m3; ss[p * 128 + c0 + 3] = s3;
    __syncthreads();

    if (t < 128) {
        float m = -INFINITY, s = 0.f;
#pragma unroll
        for (int q = 0; q < 8; ++q) {
            const float pm = mm[q * 128 + t];
            const float ps = ss[q * 128 + t];
            const float nm = fmaxf(m, pm);
            s = s * __expf(m - nm) + ps * __expf(pm - nm);
            m = nm;
        }
        W[(c << 7) + t] = LOG_B - (m + __logf(s));
    }
}

// ------------------------------------- iteration 1, row pass (su') ----------
// Second reader of G (L3-hot). Old sink_step2 passes 3-4 + tree combine,
// W loaded from global. su'[i] = LOG_A - lse_j(G+W)  (su0 cancels; verified).
__global__ __launch_bounds__(256, 2) void row_pass(
    const float* __restrict__ G, float* __restrict__ su,
    const float* __restrict__ W, float2* __restrict__ pms,
    float2* __restrict__ lms, int* __restrict__ cnt)
{
    __shared__ float Wlds[64];
    __shared__ float Rlds[256];
    __shared__ float r_arr[256 * 17];
    __shared__ int lastf;

    const int t  = threadIdx.x;
    const int b  = blockIdx.x;
    const int j0 = b << 6;
    const int jq = t & 15;
    const int is = t >> 4;

    if (t < 64) Wlds[t] = W[j0 + t];
    __syncthreads();

    const float4* G4 = (const float4*)G;
    float4 tile[16];
#pragma unroll
    for (int k = 0; k < 16; ++k) {
        int i = is + (k << 4);
        tile[k] = G4[i * 8192 + (j0 >> 2) + jq];
    }
#pragma unroll
    for (int k = 0; k < 16; ++k) PIN4(tile[k]);

    float4 Wq = make_float4(Wlds[4 * jq + 0], Wlds[4 * jq + 1],
                            Wlds[4 * jq + 2], Wlds[4 * jq + 3]);

    // ---- row max of (G+W) over this block's 64 j ----
#pragma unroll
    for (int k = 0; k < 16; ++k) {
        float a0 = tile[k].x + Wq.x;
        float a1 = tile[k].y + Wq.y;
        float a2 = tile[k].z + Wq.z;
        float a3 = tile[k].w + Wq.w;
        r_arr[(is + (k << 4)) * 17 + jq] = fmaxf(fmaxf(a0, a1), fmaxf(a2, a3));
    }
    __syncthreads();
    {
        float R = -INFINITY;
#pragma unroll
        for (int p = 0; p < 16; ++p) R = fmaxf(R, r_arr[t * 17 + p]);
        Rlds[t] = R;
    }
    __syncthreads();

    // ---- row expsum vs R ----
#pragma unroll
    for (int k = 0; k < 16; ++k) {
        float Rr = Rlds[is + (k << 4)];
        float s = __expf(tile[k].x + Wq.x - Rr) + __expf(tile[k].y + Wq.y - Rr) +
                  __expf(tile[k].z + Wq.z - Rr) + __expf(tile[k].w + Wq.w - Rr);
        r_arr[(is + (k << 4)) * 17 + jq] = s;
    }
    __syncthreads();
    {
        float s = 0.f;
#pragma unroll
        for (int p = 0; p < 16; ++p) s += r_arr[t * 17 + p];
        pms[(b << 8) + t] = make_float2(Rlds[t], s);
    }

    // ---- two-level cross-block lse combine ----
    __threadfence();
    if (t == 0) lastf = (atomicAdd(cnt + (b >> 4), 1) == 15);
    __syncthreads();
    if (!lastf) return;
    __threadfence();

    const int g = b >> 4;
    {
        float cm[4] = {-INFINITY, -INFINITY, -INFINITY, -INFINITY};
        float cs[4] = {0.f, 0.f, 0.f, 0.f};
#pragma unroll
        for (int p = 0; p < 16; p += 4) {
#pragma unroll
            for (int c = 0; c < 4; ++c) {
                float2 v = pms[(((g << 4) + p + c) << 8) + t];
                float nm = fmaxf(cm[c], v.x);
                cs[c] = cs[c] * __expf(cm[c] - nm) + v.y * __expf(v.x - nm);
                cm[c] = nm;
            }
        }
        float m = cm[0], s = cs[0];
#pragma unroll
        for (int c = 1; c < 4; ++c) {
            float nm = fmaxf(m, cm[c]);
            s = s * __expf(m - nm) + cs[c] * __expf(cm[c] - nm);
            m = nm;
        }
        lms[(g << 8) + t] = make_float2(m, s);
    }

    __threadfence();
    if (t == 0) lastf = (atomicAdd(cnt + 32, 1) == 31);
    __syncthreads();
    if (!lastf) return;
    __threadfence();

    {
        float cm[4] = {-INFINITY, -INFINITY, -INFINITY, -INFINITY};
        float cs[4] = {0.f, 0.f, 0.f, 0.f};
#pragma unroll
        for (int p = 0; p < 32; p += 4) {
#pragma unroll
            for (int c = 0; c < 4; ++c) {
                float2 v = lms[((p + c) << 8) + t];
                float nm = fmaxf(cm[c], v.x);
                cs[c] = cs[c] * __expf(cm[c] - nm) + v.y * __expf(v.x - nm);
                cm[c] = nm;
            }
        }
        float m = cm[0], s = cs[0];
#pragma unroll
        for (int c = 1; c < 4; ++c) {
            float nm = fmaxf(m, cm[c]);
            s = s * __expf(m - nm) + cs[c] * __expf(cm[c] - nm);
            m = nm;
        }
        su[t] = LOG_A - (m + __logf(s));
    }
}

// -------------------------------------------- iteration (fast, 2..100) ------
// E-reuse: tile := exp((G+su) - M_j) after the column pass; phase R is one
// fma/elem vs 1/S_j; cross-block combine = plain sums (row sums >= a*b).
// su'[i] = LOG_A - LOG_B + su[i] - log(tot_i), tot_i = sum_j E_ij / S_j.
__global__ __launch_bounds__(256, 2) void sink_fast(
    const float* __restrict__ G, float* __restrict__ su,
    float* __restrict__ W, float* __restrict__ prow, float* __restrict__ lrow,
    int* __restrict__ cnt, const int* __restrict__ active)
{
    if (active[0] == 0) return;
    __shared__ float su_lds[256];
    __shared__ float comb[1024];
    __shared__ float Mlds[64];
    __shared__ float ecol[64];
    __shared__ float s_arr[256 * 17];
    __shared__ int lastf;

    const int t  = threadIdx.x;
    const int b  = blockIdx.x;
    const int j0 = b << 6;
    const int jq = t & 15;
    const int is = t >> 4;

    su_lds[t] = su[t];
    __syncthreads();

    const float4* G4 = (const float4*)G;
    float4 tile[16];
#pragma unroll
    for (int k = 0; k < 16; ++k) {
        int i = is + (k << 4);
        float4 g = G4[i * 8192 + (j0 >> 2) + jq];
        float s = su_lds[i];
        tile[k] = make_float4(g.x + s, g.y + s, g.z + s, g.w + s);
    }
#pragma unroll
    for (int k = 0; k < 16; ++k) PIN4(tile[k]);

    // column max over i
    float m0 = -INFINITY, m1 = -INFINITY, m2 = -INFINITY, m3 = -INFINITY;
#pragma unroll
    for (int k = 0; k < 16; ++k) {
        m0 = fmaxf(m0, tile[k].x);
        m1 = fmaxf(m1, tile[k].y);
        m2 = fmaxf(m2, tile[k].z);
        m3 = fmaxf(m3, tile[k].w);
    }
    ((float4*)comb)[(is << 4) + jq] = make_float4(m0, m1, m2, m3);
    __syncthreads();
    if (t < 64) {
        float m = -INFINITY;
#pragma unroll
        for (int s = 0; s < 16; ++s) m = fmaxf(m, comb[(s << 6) + t]);
        Mlds[t] = m;
    }
    __syncthreads();
    float4 Mq = make_float4(Mlds[4 * jq + 0], Mlds[4 * jq + 1],
                            Mlds[4 * jq + 2], Mlds[4 * jq + 3]);

    // E = exp(tile - M), column sums S
    float s0 = 0.f, s1 = 0.f, s2 = 0.f, s3 = 0.f;
#pragma unroll
    for (int k = 0; k < 16; ++k) {
        tile[k].x = __expf(tile[k].x - Mq.x); s0 += tile[k].x;
        tile[k].y = __expf(tile[k].y - Mq.y); s1 += tile[k].y;
        tile[k].z = __expf(tile[k].z - Mq.z); s2 += tile[k].z;
        tile[k].w = __expf(tile[k].w - Mq.w); s3 += tile[k].w;
    }
    ((float4*)comb)[(is << 4) + jq] = make_float4(s0, s1, s2, s3);
    __syncthreads();
    if (t < 64) {
        float ssum = 0.f;
#pragma unroll
        for (int s = 0; s < 16; ++s) ssum += comb[(s << 6) + t];
        W[j0 + t] = LOG_B - (Mlds[t] + __logf(ssum));
        ecol[t]   = 1.0f / ssum;            // = exp(W+M)/b
    }
    __syncthreads();
    float4 Eq = make_float4(ecol[4 * jq + 0], ecol[4 * jq + 1],
                            ecol[4 * jq + 2], ecol[4 * jq + 3]);

    // phase R: row partial = dot(E_rowslice, 1/S)
#pragma unroll
    for (int k = 0; k < 16; ++k) {
        float r = tile[k].x * Eq.x + tile[k].y * Eq.y +
                  tile[k].z * Eq.z + tile[k].w * Eq.w;
        s_arr[(is + (k << 4)) * 17 + jq] = r;
    }
    __syncthreads();
    {
        float s = 0.f;
#pragma unroll
        for (int p = 0; p < 16; ++p) s += s_arr[t * 17 + p];
        prow[(b << 8) + t] = s;
    }

    // two-level plain-sum combine
    __threadfence();
    if (t == 0) lastf = (atomicAdd(cnt + (b >> 4), 1) == 15);
    __syncthreads();
    if (!lastf) return;
    __threadfence();

    const int g = b >> 4;
    {
        float acc = 0.f;
#pragma unroll
        for (int p = 0; p < 16; ++p) acc += prow[(((g << 4) + p) << 8) + t];
        lrow[(g << 8) + t] = acc;
    }
    __threadfence();
    if (t == 0) lastf = (atomicAdd(cnt + 32, 1) == 31);
    __syncthreads();
    if (!lastf) return;
    __threadfence();
    {
        float tot = 0.f;
#pragma unroll
        for (int p = 0; p < 32; ++p) tot += lrow[(p << 8) + t];
        su[t] = (LOG_A - LOG_B) + su_lds[t] - __logf(tot);
    }
}

// --------------------------------------------- absorb-step column error -----
__global__ __launch_bounds__(256, 2) void sink_colerr(
    const float* __restrict__ G, const float* __restrict__ su,
    const float* __restrict__ W, unsigned* __restrict__ colerr, int slot,
    int* __restrict__ counter, int* __restrict__ active, int gated)
{
    if (gated && active[0] == 0) return;
    __shared__ float su_lds[256];
    __shared__ float comb[1024];
    __shared__ float Mlds[64];

    const int t  = threadIdx.x;
    const int b  = blockIdx.x;
    const int j0 = b << 6;
    const int jq = t & 15;
    const int is = t >> 4;

    su_lds[t] = su[t];
    __syncthreads();

    const float4* G4 = (const float4*)G;
    float4 tile[16];
#pragma unroll
    for (int k = 0; k < 16; ++k) {
        int i = is + (k << 4);
        tile[k] = G4[i * 8192 + (j0 >> 2) + jq];
    }
#pragma unroll
    for (int k = 0; k < 16; ++k) PIN4(tile[k]);

    float m0 = -INFINITY, m1 = -INFINITY, m2 = -INFINITY, m3 = -INFINITY;
#pragma unroll
    for (int k = 0; k < 16; ++k) {
        float sk = su_lds[is + (k << 4)];
        m0 = fmaxf(m0, tile[k].x + sk);
        m1 = fmaxf(m1, tile[k].y + sk);
        m2 = fmaxf(m2, tile[k].z + sk);
        m3 = fmaxf(m3, tile[k].w + sk);
    }
    ((float4*)comb)[(is << 4) + jq] = make_float4(m0, m1, m2, m3);
    __syncthreads();
    if (t < 64) {
        float m = -INFINITY;
#pragma unroll
        for (int s = 0; s < 16; ++s) m = fmaxf(m, comb[(s << 6) + t]);
        Mlds[t] = m;
    }
    __syncthreads();
    float4 Mq = make_float4(Mlds[4 * jq + 0], Mlds[4 * jq + 1],
                            Mlds[4 * jq + 2], Mlds[4 * jq + 3]);
    float s0 = 0.f, s1 = 0.f, s2 = 0.f, s3 = 0.f;
#pragma unroll
    for (int k = 0; k < 16; ++k) {
        float sk = su_lds[is + (k << 4)];
        s0 += __expf(tile[k].x + sk - Mq.x);
        s1 += __expf(tile[k].y + sk - Mq.y);
        s2 += __expf(tile[k].z + sk - Mq.z);
        s3 += __expf(tile[k].w + sk - Mq.w);
    }
    ((float4*)comb)[(is << 4) + jq] = make_float4(s0, s1, s2, s3);
    __syncthreads();
    if (t < 64) {
        float ssum = 0.f;
#pragma unroll
        for (int s = 0; s < 16; ++s) ssum += comb[(s << 6) + t];
        float Aj  = Mlds[t] + __logf(ssum);
        float col = __expf(Aj + W[j0 + t]);
        float d   = fabsf(col - BVAL);
        for (int off = 32; off; off >>= 1) d = fmaxf(d, __shfl_down(d, off));
        if (t == 0) {
            atomicMax(colerr + slot, __float_as_uint(d));
            __threadfence();
            if (atomicAdd(counter, 1) == 511) {
                __threadfence();
                unsigned e = atomicMax(colerr + slot, 0u);
                active[0] = (__uint_as_float(e) > 0.005f) ? 1 : 0;
            }
        }
    }
}

// ------------------------------------------------------------- finalize -----
__global__ __launch_bounds__(256) void finalize_k(
    const float* __restrict__ G, const float* __restrict__ su,
    const float* __restrict__ W, const float* __restrict__ nx,
    const float* __restrict__ ny, float* __restrict__ out)
{
    __shared__ float su_lds[256], nx_lds[256];
    __shared__ float red[4];
    const int t = threadIdx.x, b = blockIdx.x;
    const int j0 = b << 7;
    const int jq = t & 31;
    const int ig = t >> 5;
    su_lds[t] = su[t];
    nx_lds[t] = nx[t];
    __syncthreads();

    const float4* G4 = (const float4*)G;
    const float4 Wq  = ((const float4*)W)[(j0 >> 2) + jq];
    const float4 nyq = ((const float4*)ny)[(j0 >> 2) + jq];
    const int jbase = 1 + j0 + (jq << 2);
    float acc = 0.f;
#pragma unroll 4
    for (int it = 0; it < 32; ++it) {
        const int i = ig + (it << 3);
        float4 g = G4[i * 8192 + (j0 >> 2) + jq];
        const float si = su_lds[i], nxi = nx_lds[i];
        float v0 = __expf(g.x + si + Wq.x);
        float v1 = __expf(g.y + si + Wq.y);
        float v2 = __expf(g.z + si + Wq.z);
        float v3 = __expf(g.w + si + Wq.w);
        float* o = out + jbase + (size_t)i * 32768;
        __builtin_nontemporal_store(v0, o + 0);
        __builtin_nontemporal_store(v1, o + 1);
        __builtin_nontemporal_store(v2, o + 2);
        __builtin_nontemporal_store(v3, o + 3);
        acc += v0 * (nxi + nyq.x - 0.05f * g.x) +
               v1 * (nxi + nyq.y - 0.05f * g.y) +
               v2 * (nxi + nyq.z - 0.05f * g.z) +
               v3 * (nxi + nyq.w - 0.05f * g.w);
    }
    for (int off = 32; off; off >>= 1) acc += __shfl_down(acc, off);
    if ((t & 63) == 0) red[t >> 6] = acc;
    __syncthreads();
    if (t == 0) atomicAdd(out, red[0] + red[1] + red[2] + red[3]);
}

// ---------------------------------------------------------------- host ------
extern "C" void kernel_launch(void* const* d_in, const int* in_sizes, int n_in,
                              void* d_out, int out_size, void* d_ws, size_t ws_size,
                              hipStream_t stream)
{
    const float* x = (const float*)d_in[0];   // [256, 384]
    const float* y = (const float*)d_in[1];   // [32768, 384]
    float* out = (float*)d_out;               // [1 + 256*32768]

    float* ws   = (float*)d_ws;
    float* G    = ws;                 // 8388608
    float* Wv   = G + 8388608;        // 32768
    float* su   = Wv + 32768;         // 256
    float* nx   = su + 256;           // 256
    float* ny   = nx + 256;           // 32768
    float2* pms = (float2*)(ny + 32768);           // 131072 float2 (iter 1)
    float2* lms = pms + 131072;                    // 8192 float2
    float* prow = (float*)(lms + 8192);            // 131072 (iters 2+)
    float* lrow = prow + 131072;                   // 8192
    unsigned* colerr = (unsigned*)(lrow + 8192);   // 2
    int* active   = (int*)(colerr + 2);            // 1
    int* counters = active + 1;                    // 4096

    init_k<<<8257, 256, 0, stream>>>(x, y, nx, ny, su, colerr, active, counters, out);
    gemm_k<<<dim3(256, 2), 256, 0, stream>>>(x, y, G);

    // iteration 1 (log-safe): row-contiguous column pass, then L3-hot row pass
    col_pass<<<256, 256, 0, stream>>>(G, su, Wv);
    row_pass<<<512, 256, 0, stream>>>(G, su, Wv, pms, lms, counters + 0);
    sink_colerr<<<512, 256, 0, stream>>>(G, su, Wv, colerr, 0, counters + 4000, active, 0);

    for (int tt = 2; tt <= 100; ++tt) {
        sink_fast<<<512, 256, 0, stream>>>(G, su, Wv, prow, lrow,
                                           counters + 40 * (tt - 1), active);
        if (tt == 51)   // absorb at cpt_n=51: error check gates the rest
            sink_colerr<<<512, 256, 0, stream>>>(G, su, Wv, colerr, 1,
                                                 counters + 4001, active, 1);
    }

    finalize_k<<<256, 256, 0, stream>>>(G, su, Wv, nx, ny, out);
}

// Round 6
// 386.205 us; speedup vs baseline: 1.0247x; 1.0247x over previous
//
#include <hip/hip_runtime.h>
#include <math.h>

// ---------------------------------------------------------------------------
// Sinkhorn ETP (FASTopic) on MI355X.
// n=256 topics, m=32768 words, D=384.
//
//   log_K0[i,j] = G[i,j] + su0[i] + sv0[j],  G = 40 * x@y^T
//   Per iteration:  W[j] = log_b - lse_i(G+su);  su'[i] = log_a - lse_j(G+W)
//   Final: transp[i,j] = exp(G+su[i]+W[j]); M = nx[i]+ny[j]-0.05*G;
//          loss = sum(transp*M)
//
// R8: E-reuse fast path (iters 2..100).
// R9-R13 mechanism hunt, closed in R13:
//   - gemm block c (linear c on XCD c%8) writes cols [128c,128c+128) -> G is
//     DIRTY in the writer XCD's L2 (32MB G == 8 x 4MB aggregate L2).
//   - Readers whose block->XCD matches the writer's XCD (col_pass, finalize:
//     128-col slabs, 256-grid) hit local dirty L2 -> fast. Verified R13.
//   - 512-grid 64-col-slab readers (old sink_step, R13 row_pass): block b on
//     XCD b%8 wants data written by gemm block b/2 on XCD (b/2)%8 - mismatch
//     for 14/16 blocks. Miss-local + dirty-in-REMOTE-non-coherent-L2 = slow
//     cross-XCD probe path at ~240 GB/s -> 17MB = 75us. The signature
//     followed this mapping (not the code) through 5 rewrites.
//   - sink_fast/colerr were fast only because the first 512-grid reader
//     repatriates slabs into reader-aligned L2s.
//
// R14: XCD-align ALL 512-grid G readers. HW block L (XCD L%8) processes slab
//   b = swz512(L) with (b>>1)%8 == L%8 (bijective) -> every G read is a
//   local-L2 hit; no repatriation, no cross-XCD probes. col/row split dropped
//   (one-kernel log-safe sink_step2 restored). gemm G write back to plain
//   stores (keep G dirty-local; nt proved inert for the read path).
// Predicted: sink_step2 75 -> 3-6us (FETCH 17MB -> <3MB), top-5 becomes
// gemm/init/finalize, total ~305-315us. Falsifier: still ~70us -> XCD
// round-robin assumption wrong -> R15 persistent cooperative kernel.
// ---------------------------------------------------------------------------

#define N_TOPIC 256
#define N_WORD  32768

static constexpr float LOG_A = -5.545177444479562f;    // log(1/256 + 1e-30)
static constexpr float LOG_B = -10.397207708399179f;   // log(1/32768 + 1e-30)
static constexpr float BVAL  = 3.0517578125e-05f;      // 1/32768

typedef float f32x4 __attribute__((ext_vector_type(4)));
typedef short bf16x8 __attribute__((ext_vector_type(8)));

// Keep a float4's lanes pinned in VGPRs (opaque use+def; no remat).
#define PIN4(v) asm volatile("" : "+v"((v).x), "+v"((v).y), "+v"((v).z), "+v"((v).w))

// XCD-aligning slab swizzle for 512-block G readers: HW block L runs on XCD
// L%8 (round-robin dispatch, verified by R13's col_pass/finalize being fast);
// slab b lives dirty on XCD (b>>1)%8 (gemm writer). Choose b with
// (b>>1)%8 == L%8, bijective over [0,512).
static __device__ __forceinline__ int swz512(int L)
{
    const int x = L & 7;        // target XCD
    const int q = L >> 3;       // 0..63
    return (x << 1) + ((q >> 1) << 4) + (q & 1);
}

// ---------------------------------------------------------------- init ------
__global__ __launch_bounds__(256) void init_k(
    const float* __restrict__ x, const float* __restrict__ y,
    float* __restrict__ nx, float* __restrict__ ny, float* __restrict__ su,
    unsigned* __restrict__ colerr, int* __restrict__ active,
    int* __restrict__ counters, float* __restrict__ out)
{
    const int b = blockIdx.x, t = threadIdx.x;
    const int w = t >> 6, l = t & 63;
    if (b < 8192) {                       // ||y_j||^2, 4 rows/block (wave per row)
        const int r = (b << 2) + w;
        const float4* y4 = (const float4*)y;
        float4 v = y4[r * 96 + l];
        float s = v.x * v.x + v.y * v.y + v.z * v.z + v.w * v.w;
        if (l < 32) {
            float4 u = y4[r * 96 + 64 + l];
            s += u.x * u.x + u.y * u.y + u.z * u.z + u.w * u.w;
        }
        for (int off = 32; off; off >>= 1) s += __shfl_down(s, off);
        if (l == 0) ny[r] = s;
    } else if (b < 8256) {                // ||x_i||^2 and su0 = -20*nx
        const int r = ((b - 8192) << 2) + w;
        const float4* x4 = (const float4*)x;
        float4 v = x4[r * 96 + l];
        float s = v.x * v.x + v.y * v.y + v.z * v.z + v.w * v.w;
        if (l < 32) {
            float4 u = x4[r * 96 + 64 + l];
            s += u.x * u.x + u.y * u.y + u.z * u.z + u.w * u.w;
        }
        for (int off = 32; off; off >>= 1) s += __shfl_down(s, off);
        if (l == 0) { nx[r] = s; su[r] = -20.f * s; }
    } else {
        for (int k = t; k < 4096; k += 256) counters[k] = 0;
        if (t == 0) { colerr[0] = 0u; colerr[1] = 0u; active[0] = 1; out[0] = 0.f; }
    }
}

// ---------------------------------------------------------------- gemm ------
// Exact 3-way bf16 truncation split: v = b0 + b1 + b2 (+ r3, |r3|<=2^-27|v|).
static __device__ __forceinline__ void split3(float v, ushort& h0, ushort& h1, ushort& h2)
{
    unsigned u0 = __float_as_uint(v);
    h0 = (ushort)(u0 >> 16);
    float r1 = v - __uint_as_float(u0 & 0xFFFF0000u);
    unsigned u1 = __float_as_uint(r1);
    h1 = (ushort)(u1 >> 16);
    float r2 = r1 - __uint_as_float(u1 & 0xFFFF0000u);
    h2 = (ushort)(__float_as_uint(r2) >> 16);
}

// Block tile 128i x 128j, K-chunks of 32, grid (256 jb, 2 ib) = 512 blocks.
// Frag layouts (m89/m91-verified); y is [j][k] row-major = B^T identical frag.
// Plain stores: G stays dirty in the writer XCD's L2 (readers are aligned).
__global__ __launch_bounds__(256, 1) void gemm_k(
    const float* __restrict__ x, const float* __restrict__ y, float* __restrict__ G)
{
    __shared__ __align__(16) ushort xs0[5120], xs1[5120], xs2[5120];
    __shared__ __align__(16) ushort ys0[5120], ys1[5120], ys2[5120];

    const int t   = threadIdx.x;
    const int jb  = blockIdx.x << 7;   // 128-col slab
    const int ib  = blockIdx.y << 7;   // 128-row slab
    const int w   = t >> 6;            // wave 0..3
    const int ln  = t & 63;
    const int q   = ln >> 4;           // quad 0..3
    const int l15 = ln & 15;

    const float4* x4 = (const float4*)x;
    const float4* y4 = (const float4*)y;

    f32x4 acc[2][8];
#pragma unroll
    for (int mi = 0; mi < 2; ++mi)
#pragma unroll
        for (int nj = 0; nj < 8; ++nj) acc[mi][nj] = (f32x4){0.f, 0.f, 0.f, 0.f};

    for (int kc = 0; kc < 12; ++kc) {
        __syncthreads();
#pragma unroll
        for (int p = 0; p < 4; ++p) {
            const int f  = (t << 2) + p;       // 0..1023 float4 slots
            const int r  = f >> 3, c4 = f & 7; // row, k-quad
            const int o  = r * 40 + (c4 << 2);
            float4 vx = x4[(ib + r) * 96 + (kc << 3) + c4];
            ushort a0,a1,a2,b0,b1,b2,c0,c1,c2,d0,d1,d2;
            split3(vx.x, a0,a1,a2); split3(vx.y, b0,b1,b2);
            split3(vx.z, c0,c1,c2); split3(vx.w, d0,d1,d2);
            *(ushort4*)&xs0[o] = make_ushort4(a0,b0,c0,d0);
            *(ushort4*)&xs1[o] = make_ushort4(a1,b1,c1,d1);
            *(ushort4*)&xs2[o] = make_ushort4(a2,b2,c2,d2);
            float4 vy = y4[(jb + r) * 96 + (kc << 3) + c4];
            split3(vy.x, a0,a1,a2); split3(vy.y, b0,b1,b2);
            split3(vy.z, c0,c1,c2); split3(vy.w, d0,d1,d2);
            *(ushort4*)&ys0[o] = make_ushort4(a0,b0,c0,d0);
            *(ushort4*)&ys1[o] = make_ushort4(a1,b1,c1,d1);
            *(ushort4*)&ys2[o] = make_ushort4(a2,b2,c2,d2);
        }
        __syncthreads();

        bf16x8 A[3][2];
#pragma unroll
        for (int mi = 0; mi < 2; ++mi) {
            const int off = ((w << 5) + (mi << 4) + l15) * 40 + (q << 3);
            A[0][mi] = *(const bf16x8*)&xs0[off];
            A[1][mi] = *(const bf16x8*)&xs1[off];
            A[2][mi] = *(const bf16x8*)&xs2[off];
        }
#pragma unroll
        for (int nj = 0; nj < 8; ++nj) {
            const int off = ((nj << 4) + l15) * 40 + (q << 3);
            bf16x8 B0 = *(const bf16x8*)&ys0[off];
            bf16x8 B1 = *(const bf16x8*)&ys1[off];
            bf16x8 B2 = *(const bf16x8*)&ys2[off];
#pragma unroll
            for (int mi = 0; mi < 2; ++mi) {
                f32x4 c = acc[mi][nj];
                c = __builtin_amdgcn_mfma_f32_16x16x32_bf16(A[0][mi], B0, c, 0, 0, 0);
                c = __builtin_amdgcn_mfma_f32_16x16x32_bf16(A[0][mi], B1, c, 0, 0, 0);
                c = __builtin_amdgcn_mfma_f32_16x16x32_bf16(A[1][mi], B0, c, 0, 0, 0);
                c = __builtin_amdgcn_mfma_f32_16x16x32_bf16(A[1][mi], B1, c, 0, 0, 0);
                c = __builtin_amdgcn_mfma_f32_16x16x32_bf16(A[0][mi], B2, c, 0, 0, 0);
                c = __builtin_amdgcn_mfma_f32_16x16x32_bf16(A[2][mi], B0, c, 0, 0, 0);
                acc[mi][nj] = c;
            }
        }
    }
#pragma unroll
    for (int mi = 0; mi < 2; ++mi) {
        const int gi0 = ib + (w << 5) + (mi << 4) + (q << 2);
#pragma unroll
        for (int nj = 0; nj < 8; ++nj) {
            const int gj = jb + (nj << 4) + l15;
#pragma unroll
            for (int r = 0; r < 4; ++r)
                G[(size_t)(gi0 + r) * 32768 + gj] = 40.f * acc[mi][nj][r];
        }
    }
}

// -------------------------------------------- iteration 1 (log-safe) --------
// R11 structure (sink_fast-shaped exact lse) + R14 XCD-aligned slab swizzle.
//   1) colmax M_j over (G+su)   2) colexpsum -> W_j
//   3) rowmax R_i over (G+W)    4) rowexpsum; cross-block lse combine.
__global__ __launch_bounds__(256, 2) void sink_step2(
    const float* __restrict__ G, float* __restrict__ su,
    float* __restrict__ W, float2* __restrict__ pms, float2* __restrict__ lms,
    int* __restrict__ cnt)
{
    __shared__ float su_lds[256];
    __shared__ float comb[1024];
    __shared__ float Mlds[64];
    __shared__ float Wlds[64];
    __shared__ float Rlds[256];
    __shared__ float r_arr[256 * 17];
    __shared__ int lastf;

    const int t  = threadIdx.x;
    const int b  = swz512(blockIdx.x);     // R14: slab aligned to this XCD's L2
    const int j0 = b << 6;
    const int jq = t & 15;
    const int is = t >> 4;

    su_lds[t] = su[t];
    __syncthreads();

    const float4* G4 = (const float4*)G;
    float4 tile[16];
#pragma unroll
    for (int k = 0; k < 16; ++k) {
        int i = is + (k << 4);
        tile[k] = G4[i * 8192 + (j0 >> 2) + jq];
    }
#pragma unroll
    for (int k = 0; k < 16; ++k) PIN4(tile[k]);

    // ---- pass 1: column max of (G+su) over i ----
    float m0 = -INFINITY, m1 = -INFINITY, m2 = -INFINITY, m3 = -INFINITY;
#pragma unroll
    for (int k = 0; k < 16; ++k) {
        float sk = su_lds[is + (k << 4)];
        m0 = fmaxf(m0, tile[k].x + sk);
        m1 = fmaxf(m1, tile[k].y + sk);
        m2 = fmaxf(m2, tile[k].z + sk);
        m3 = fmaxf(m3, tile[k].w + sk);
    }
    ((float4*)comb)[(is << 4) + jq] = make_float4(m0, m1, m2, m3);
    __syncthreads();
    if (t < 64) {
        float m = -INFINITY;
#pragma unroll
        for (int s = 0; s < 16; ++s) m = fmaxf(m, comb[(s << 6) + t]);
        Mlds[t] = m;
    }
    __syncthreads();
    float4 Mq = make_float4(Mlds[4 * jq + 0], Mlds[4 * jq + 1],
                            Mlds[4 * jq + 2], Mlds[4 * jq + 3]);

    // ---- pass 2: column expsum -> W_j ----
    float s0 = 0.f, s1 = 0.f, s2 = 0.f, s3 = 0.f;
#pragma unroll
    for (int k = 0; k < 16; ++k) {
        float sk = su_lds[is + (k << 4)];
        s0 += __expf(tile[k].x + sk - Mq.x);
        s1 += __expf(tile[k].y + sk - Mq.y);
        s2 += __expf(tile[k].z + sk - Mq.z);
        s3 += __expf(tile[k].w + sk - Mq.w);
    }
    ((float4*)comb)[(is << 4) + jq] = make_float4(s0, s1, s2, s3);
    __syncthreads();
    if (t < 64) {
        float ssum = 0.f;
#pragma unroll
        for (int s = 0; s < 16; ++s) ssum += comb[(s << 6) + t];
        float Wj = LOG_B - (Mlds[t] + __logf(ssum));
        Wlds[t] = Wj;
        W[j0 + t] = Wj;
    }
    __syncthreads();
    float4 Wq = make_float4(Wlds[4 * jq + 0], Wlds[4 * jq + 1],
                            Wlds[4 * jq + 2], Wlds[4 * jq + 3]);

    // ---- pass 3: row max of (G+W) over this block's 64 j ----
#pragma unroll
    for (int k = 0; k < 16; ++k) {
        float a0 = tile[k].x + Wq.x;
        float a1 = tile[k].y + Wq.y;
        float a2 = tile[k].z + Wq.z;
        float a3 = tile[k].w + Wq.w;
        r_arr[(is + (k << 4)) * 17 + jq] = fmaxf(fmaxf(a0, a1), fmaxf(a2, a3));
    }
    __syncthreads();
    {
        float R = -INFINITY;
#pragma unroll
        for (int p = 0; p < 16; ++p) R = fmaxf(R, r_arr[t * 17 + p]);
        Rlds[t] = R;
    }
    __syncthreads();

    // ---- pass 4: row expsum vs R ----
#pragma unroll
    for (int k = 0; k < 16; ++k) {
        float Rr = Rlds[is + (k << 4)];
        float s = __expf(tile[k].x + Wq.x - Rr) + __expf(tile[k].y + Wq.y - Rr) +
                  __expf(tile[k].z + Wq.z - Rr) + __expf(tile[k].w + Wq.w - Rr);
        r_arr[(is + (k << 4)) * 17 + jq] = s;
    }
    __syncthreads();
    {
        float s = 0.f;
#pragma unroll
        for (int p = 0; p < 16; ++p) s += r_arr[t * 17 + p];
        pms[(b << 8) + t] = make_float2(Rlds[t], s);
    }

    // ---- two-level cross-block lse combine ----
    __threadfence();
    if (t == 0) lastf = (atomicAdd(cnt + (b >> 4), 1) == 15);
    __syncthreads();
    if (!lastf) return;
    __threadfence();

    const int g = b >> 4;
    {
        float cm[4] = {-INFINITY, -INFINITY, -INFINITY, -INFINITY};
        float cs[4] = {0.f, 0.f, 0.f, 0.f};
#pragma unroll
        for (int p = 0; p < 16; p += 4) {
#pragma unroll
            for (int c = 0; c < 4; ++c) {
                float2 v = pms[(((g << 4) + p + c) << 8) + t];
                float nm = fmaxf(cm[c], v.x);
                cs[c] = cs[c] * __expf(cm[c] - nm) + v.y * __expf(v.x - nm);
                cm[c] = nm;
            }
        }
        float m = cm[0], s = cs[0];
#pragma unroll
        for (int c = 1; c < 4; ++c) {
            float nm = fmaxf(m, cm[c]);
            s = s * __expf(m - nm) + cs[c] * __expf(cm[c] - nm);
            m = nm;
        }
        lms[(g << 8) + t] = make_float2(m, s);
    }

    __threadfence();
    if (t == 0) lastf = (atomicAdd(cnt + 32, 1) == 31);
    __syncthreads();
    if (!lastf) return;
    __threadfence();

    {
        float cm[4] = {-INFINITY, -INFINITY, -INFINITY, -INFINITY};
        float cs[4] = {0.f, 0.f, 0.f, 0.f};
#pragma unroll
        for (int p = 0; p < 32; p += 4) {
#pragma unroll
            for (int c = 0; c < 4; ++c) {
                float2 v = lms[((p + c) << 8) + t];
                float nm = fmaxf(cm[c], v.x);
                cs[c] = cs[c] * __expf(cm[c] - nm) + v.y * __expf(v.x - nm);
                cm[c] = nm;
            }
        }
        float m = cm[0], s = cs[0];
#pragma unroll
        for (int c = 1; c < 4; ++c) {
            float nm = fmaxf(m, cm[c]);
            s = s * __expf(m - nm) + cs[c] * __expf(cm[c] - nm);
            m = nm;
        }
        su[t] = LOG_A - (m + __logf(s));
    }
}

// -------------------------------------------- iteration (fast, 2..100) ------
// E-reuse: tile := exp((G+su) - M_j) after the column pass; phase R is one
// fma/elem vs 1/S_j; cross-block combine = plain sums (row sums >= a*b).
// su'[i] = LOG_A - LOG_B + su[i] - log(tot_i), tot_i = sum_j E_ij / S_j.
__global__ __launch_bounds__(256, 2) void sink_fast(
    const float* __restrict__ G, float* __restrict__ su,
    float* __restrict__ W, float* __restrict__ prow, float* __restrict__ lrow,
    int* __restrict__ cnt, const int* __restrict__ active)
{
    if (active[0] == 0) return;
    __shared__ float su_lds[256];
    __shared__ float comb[1024];
    __shared__ float Mlds[64];
    __shared__ float ecol[64];
    __shared__ float s_arr[256 * 17];
    __shared__ int lastf;

    const int t  = threadIdx.x;
    const int b  = swz512(blockIdx.x);     // R14: XCD-aligned slab
    const int j0 = b << 6;
    const int jq = t & 15;
    const int is = t >> 4;

    su_lds[t] = su[t];
    __syncthreads();

    const float4* G4 = (const float4*)G;
    float4 tile[16];
#pragma unroll
    for (int k = 0; k < 16; ++k) {
        int i = is + (k << 4);
        float4 g = G4[i * 8192 + (j0 >> 2) + jq];
        float s = su_lds[i];
        tile[k] = make_float4(g.x + s, g.y + s, g.z + s, g.w + s);
    }
#pragma unroll
    for (int k = 0; k < 16; ++k) PIN4(tile[k]);

    // column max over i
    float m0 = -INFINITY, m1 = -INFINITY, m2 = -INFINITY, m3 = -INFINITY;
#pragma unroll
    for (int k = 0; k < 16; ++k) {
        m0 = fmaxf(m0, tile[k].x);
        m1 = fmaxf(m1, tile[k].y);
        m2 = fmaxf(m2, tile[k].z);
        m3 = fmaxf(m3, tile[k].w);
    }
    ((float4*)comb)[(is << 4) + jq] = make_float4(m0, m1, m2, m3);
    __syncthreads();
    if (t < 64) {
        float m = -INFINITY;
#pragma unroll
        for (int s = 0; s < 16; ++s) m = fmaxf(m, comb[(s << 6) + t]);
        Mlds[t] = m;
    }
    __syncthreads();
    float4 Mq = make_float4(Mlds[4 * jq + 0], Mlds[4 * jq + 1],
                            Mlds[4 * jq + 2], Mlds[4 * jq + 3]);

    // E = exp(tile - M), column sums S
    float s0 = 0.f, s1 = 0.f, s2 = 0.f, s3 = 0.f;
#pragma unroll
    for (int k = 0; k < 16; ++k) {
        tile[k].x = __expf(tile[k].x - Mq.x); s0 += tile[k].x;
        tile[k].y = __expf(tile[k].y - Mq.y); s1 += tile[k].y;
        tile[k].z = __expf(tile[k].z - Mq.z); s2 += tile[k].z;
        tile[k].w = __expf(tile[k].w - Mq.w); s3 += tile[k].w;
    }
    ((float4*)comb)[(is << 4) + jq] = make_float4(s0, s1, s2, s3);
    __syncthreads();
    if (t < 64) {
        float ssum = 0.f;
#pragma unroll
        for (int s = 0; s < 16; ++s) ssum += comb[(s << 6) + t];
        W[j0 + t] = LOG_B - (Mlds[t] + __logf(ssum));
        ecol[t]   = 1.0f / ssum;            // = exp(W+M)/b
    }
    __syncthreads();
    float4 Eq = make_float4(ecol[4 * jq + 0], ecol[4 * jq + 1],
                            ecol[4 * jq + 2], ecol[4 * jq + 3]);

    // phase R: row partial = dot(E_rowslice, 1/S)
#pragma unroll
    for (int k = 0; k < 16; ++k) {
        float r = tile[k].x * Eq.x + tile[k].y * Eq.y +
                  tile[k].z * Eq.z + tile[k].w * Eq.w;
        s_arr[(is + (k << 4)) * 17 + jq] = r;
    }
    __syncthreads();
    {
        float s = 0.f;
#pragma unroll
        for (int p = 0; p < 16; ++p) s += s_arr[t * 17 + p];
        prow[(b << 8) + t] = s;
    }

    // two-level plain-sum combine
    __threadfence();
    if (t == 0) lastf = (atomicAdd(cnt + (b >> 4), 1) == 15);
    __syncthreads();
    if (!lastf) return;
    __threadfence();

    const int g = b >> 4;
    {
        float acc = 0.f;
#pragma unroll
        for (int p = 0; p < 16; ++p) acc += prow[(((g << 4) + p) << 8) + t];
        lrow[(g << 8) + t] = acc;
    }
    __threadfence();
    if (t == 0) lastf = (atomicAdd(cnt + 32, 1) == 31);
    __syncthreads();
    if (!lastf) return;
    __threadfence();
    {
        float tot = 0.f;
#pragma unroll
        for (int p = 0; p < 32; ++p) tot += lrow[(p << 8) + t];
        su[t] = (LOG_A - LOG_B) + su_lds[t] - __logf(tot);
    }
}

// --------------------------------------------- absorb-step column error -----
__global__ __launch_bounds__(256, 2) void sink_colerr(
    const float* __restrict__ G, const float* __restrict__ su,
    const float* __restrict__ W, unsigned* __restrict__ colerr, int slot,
    int* __restrict__ counter, int* __restrict__ active, int gated)
{
    if (gated && active[0] == 0) return;
    __shared__ float su_lds[256];
    __shared__ float comb[1024];
    __shared__ float Mlds[64];

    const int t  = threadIdx.x;
    const int b  = swz512(blockIdx.x);     // R14: XCD-aligned slab
    const int j0 = b << 6;
    const int jq = t & 15;
    const int is = t >> 4;

    su_lds[t] = su[t];
    __syncthreads();

    const float4* G4 = (const float4*)G;
    float4 tile[16];
#pragma unroll
    for (int k = 0; k < 16; ++k) {
        int i = is + (k << 4);
        tile[k] = G4[i * 8192 + (j0 >> 2) + jq];
    }
#pragma unroll
    for (int k = 0; k < 16; ++k) PIN4(tile[k]);

    float m0 = -INFINITY, m1 = -INFINITY, m2 = -INFINITY, m3 = -INFINITY;
#pragma unroll
    for (int k = 0; k < 16; ++k) {
        float sk = su_lds[is + (k << 4)];
        m0 = fmaxf(m0, tile[k].x + sk);
        m1 = fmaxf(m1, tile[k].y + sk);
        m2 = fmaxf(m2, tile[k].z + sk);
        m3 = fmaxf(m3, tile[k].w + sk);
    }
    ((float4*)comb)[(is << 4) + jq] = make_float4(m0, m1, m2, m3);
    __syncthreads();
    if (t < 64) {
        float m = -INFINITY;
#pragma unroll
        for (int s = 0; s < 16; ++s) m = fmaxf(m, comb[(s << 6) + t]);
        Mlds[t] = m;
    }
    __syncthreads();
    float4 Mq = make_float4(Mlds[4 * jq + 0], Mlds[4 * jq + 1],
                            Mlds[4 * jq + 2], Mlds[4 * jq + 3]);
    float s0 = 0.f, s1 = 0.f, s2 = 0.f, s3 = 0.f;
#pragma unroll
    for (int k = 0; k < 16; ++k) {
        float sk = su_lds[is + (k << 4)];
        s0 += __expf(tile[k].x + sk - Mq.x);
        s1 += __expf(tile[k].y + sk - Mq.y);
        s2 += __expf(tile[k].z + sk - Mq.z);
        s3 += __expf(tile[k].w + sk - Mq.w);
    }
    ((float4*)comb)[(is << 4) + jq] = make_float4(s0, s1, s2, s3);
    __syncthreads();
    if (t < 64) {
        float ssum = 0.f;
#pragma unroll
        for (int s = 0; s < 16; ++s) ssum += comb[(s << 6) + t];
        float Aj  = Mlds[t] + __logf(ssum);
        float col = __expf(Aj + W[j0 + t]);
        float d   = fabsf(col - BVAL);
        for (int off = 32; off; off >>= 1) d = fmaxf(d, __shfl_down(d, off));
        if (t == 0) {
            atomicMax(colerr + slot, __float_as_uint(d));
            __threadfence();
            if (atomicAdd(counter, 1) == 511) {
                __threadfence();
                unsigned e = atomicMax(colerr + slot, 0u);
                active[0] = (__uint_as_float(e) > 0.005f) ? 1 : 0;
            }
        }
    }
}

// ------------------------------------------------------------- finalize -----
// 256-grid 128-col slabs: already XCD-aligned with gemm (b%8 == b%8).
// transp writes stay nontemporal (out is never re-read on device).
__global__ __launch_bounds__(256) void finalize_k(
    const float* __restrict__ G, const float* __restrict__ su,
    const float* __restrict__ W, const float* __restrict__ nx,
    const float* __restrict__ ny, float* __restrict__ out)
{
    __shared__ float su_lds[256], nx_lds[256];
    __shared__ float red[4];
    const int t = threadIdx.x, b = blockIdx.x;
    const int j0 = b << 7;
    const int jq = t & 31;
    const int ig = t >> 5;
    su_lds[t] = su[t];
    nx_lds[t] = nx[t];
    __syncthreads();

    const float4* G4 = (const float4*)G;
    const float4 Wq  = ((const float4*)W)[(j0 >> 2) + jq];
    const float4 nyq = ((const float4*)ny)[(j0 >> 2) + jq];
    const int jbase = 1 + j0 + (jq << 2);
    float acc = 0.f;
#pragma unroll 4
    for (int it = 0; it < 32; ++it) {
        const int i = ig + (it << 3);
        float4 g = G4[i * 8192 + (j0 >> 2) + jq];
        const float si = su_lds[i], nxi = nx_lds[i];
        float v0 = __expf(g.x + si + Wq.x);
        float v1 = __expf(g.y + si + Wq.y);
        float v2 = __expf(g.z + si + Wq.z);
        float v3 = __expf(g.w + si + Wq.w);
        float* o = out + jbase + (size_t)i * 32768;
        __builtin_nontemporal_store(v0, o + 0);
        __builtin_nontemporal_store(v1, o + 1);
        __builtin_nontemporal_store(v2, o + 2);
        __builtin_nontemporal_store(v3, o + 3);
        acc += v0 * (nxi + nyq.x - 0.05f * g.x) +
               v1 * (nxi + nyq.y - 0.05f * g.y) +
               v2 * (nxi + nyq.z - 0.05f * g.z) +
               v3 * (nxi + nyq.w - 0.05f * g.w);
    }
    for (int off = 32; off; off >>= 1) acc += __shfl_down(acc, off);
    if ((t & 63) == 0) red[t >> 6] = acc;
    __syncthreads();
    if (t == 0) atomicAdd(out, red[0] + red[1] + red[2] + red[3]);
}

// ---------------------------------------------------------------- host ------
extern "C" void kernel_launch(void* const* d_in, const int* in_sizes, int n_in,
                              void* d_out, int out_size, void* d_ws, size_t ws_size,
                              hipStream_t stream)
{
    const float* x = (const float*)d_in[0];   // [256, 384]
    const float* y = (const float*)d_in[1];   // [32768, 384]
    float* out = (float*)d_out;               // [1 + 256*32768]

    float* ws   = (float*)d_ws;
    float* G    = ws;                 // 8388608
    float* Wv   = G + 8388608;        // 32768
    float* su   = Wv + 32768;         // 256
    float* nx   = su + 256;           // 256
    float* ny   = nx + 256;           // 32768
    float2* pms = (float2*)(ny + 32768);           // 131072 float2 (iter 1)
    float2* lms = pms + 131072;                    // 8192 float2
    float* prow = (float*)(lms + 8192);            // 131072 (iters 2+)
    float* lrow = prow + 131072;                   // 8192
    unsigned* colerr = (unsigned*)(lrow + 8192);   // 2
    int* active   = (int*)(colerr + 2);            // 1
    int* counters = active + 1;                    // 4096

    init_k<<<8257, 256, 0, stream>>>(x, y, nx, ny, su, colerr, active, counters, out);
    gemm_k<<<dim3(256, 2), 256, 0, stream>>>(x, y, G);

    // iteration 1 (log-safe, XCD-aligned) + absorb error check
    sink_step2<<<512, 256, 0, stream>>>(G, su, Wv, pms, lms, counters + 0);
    sink_colerr<<<512, 256, 0, stream>>>(G, su, Wv, colerr, 0, counters + 4000, active, 0);

    for (int tt = 2; tt <= 100; ++tt) {
        sink_fast<<<512, 256, 0, stream>>>(G, su, Wv, prow, lrow,
                                           counters + 40 * (tt - 1), active);
        if (tt == 51)   // absorb at cpt_n=51: error check gates the rest
            sink_colerr<<<512, 256, 0, stream>>>(G, su, Wv, colerr, 1,
                                                 counters + 4001, active, 1);
    }

    finalize_k<<<256, 256, 0, stream>>>(G, su, Wv, nx, ny, out);
}

// Round 7
// 383.158 us; speedup vs baseline: 1.0329x; 1.0080x over previous
//
#include <hip/hip_runtime.h>
#include <math.h>

// ---------------------------------------------------------------------------
// Sinkhorn ETP (FASTopic) on MI355X.
// n=256 topics, m=32768 words, D=384.
//
//   log_K0[i,j] = G[i,j] + su0[i] + sv0[j],  G = 40 * x@y^T
//   Per iteration:  W[j] = log_b - lse_i(G+su);  su'[i] = log_a - lse_j(G+W)
//   Final: transp[i,j] = exp(G+su[i]+W[j]); M = nx[i]+ny[j]-0.05*G;
//          loss = sum(transp*M)
//
// R8: E-reuse fast path (iters 2..100).
// R9-R14 mechanism hunt, empirical law established:
//   - SLAB reads (256B/row @ 128KB pow-2 stride; any 512-block iteration
//     kernel) of not-slab-cached data run at ~240 GB/s (17MB L2-miss = 75us).
//     Payer = first slab reader, regardless of code (R11 clone), VGPRs (R9),
//     reg-pinning (R10), nt stores (R12), a prior contiguous pass over the
//     same bytes (R13), or XCD-aligned swizzle (R14 - FETCH byte-identical,
//     so L2-hit fraction is mapping-independent; all L2-placement theories
//     dead). Mechanism: slice/channel hash collapse in the L3/HBM path for
//     small strided requests; once slab-cached in L2 the pattern is harmless
//     (sink_fast ~13TB/s warm).
//   - CONTIGUOUS reads are always fast (init/col_pass/finalize, every round).
//
// R15: remove the pattern by TILING G: G_t[t][i][c], t=j/64 (512 tiles),
// i=0..255, c=j%64. Offset = t*16384 + i*64 + c. Every iteration kernel's
// block b reads tile b = contiguous 64KB (1KB per wave-load). finalize reads
// tiles 2b,2b+1. Only gemm's store addressing + readers' index arithmetic
// change - kernel structures, math, and reduction order untouched (bitwise
// identical results). Swizzle dropped (R14: neutral).
// Predicted: sink_step2 78 -> 5-12us (VALUBusy >25%), sink_fast 2.4 ->
// 1.5-2.2us/iter, total ~295-315us. Falsifier: still ~75us -> pattern theory
// dead; profile dispatch-gap/clock artifacts next.
// ---------------------------------------------------------------------------

#define N_TOPIC 256
#define N_WORD  32768

static constexpr float LOG_A = -5.545177444479562f;    // log(1/256 + 1e-30)
static constexpr float LOG_B = -10.397207708399179f;   // log(1/32768 + 1e-30)
static constexpr float BVAL  = 3.0517578125e-05f;      // 1/32768

typedef float f32x4 __attribute__((ext_vector_type(4)));
typedef short bf16x8 __attribute__((ext_vector_type(8)));

// Keep a float4's lanes pinned in VGPRs (opaque use+def; no remat).
#define PIN4(v) asm volatile("" : "+v"((v).x), "+v"((v).y), "+v"((v).z), "+v"((v).w))

// ---------------------------------------------------------------- init ------
__global__ __launch_bounds__(256) void init_k(
    const float* __restrict__ x, const float* __restrict__ y,
    float* __restrict__ nx, float* __restrict__ ny, float* __restrict__ su,
    unsigned* __restrict__ colerr, int* __restrict__ active,
    int* __restrict__ counters, float* __restrict__ out)
{
    const int b = blockIdx.x, t = threadIdx.x;
    const int w = t >> 6, l = t & 63;
    if (b < 8192) {                       // ||y_j||^2, 4 rows/block (wave per row)
        const int r = (b << 2) + w;
        const float4* y4 = (const float4*)y;
        float4 v = y4[r * 96 + l];
        float s = v.x * v.x + v.y * v.y + v.z * v.z + v.w * v.w;
        if (l < 32) {
            float4 u = y4[r * 96 + 64 + l];
            s += u.x * u.x + u.y * u.y + u.z * u.z + u.w * u.w;
        }
        for (int off = 32; off; off >>= 1) s += __shfl_down(s, off);
        if (l == 0) ny[r] = s;
    } else if (b < 8256) {                // ||x_i||^2 and su0 = -20*nx
        const int r = ((b - 8192) << 2) + w;
        const float4* x4 = (const float4*)x;
        float4 v = x4[r * 96 + l];
        float s = v.x * v.x + v.y * v.y + v.z * v.z + v.w * v.w;
        if (l < 32) {
            float4 u = x4[r * 96 + 64 + l];
            s += u.x * u.x + u.y * u.y + u.z * u.z + u.w * u.w;
        }
        for (int off = 32; off; off >>= 1) s += __shfl_down(s, off);
        if (l == 0) { nx[r] = s; su[r] = -20.f * s; }
    } else {
        for (int k = t; k < 4096; k += 256) counters[k] = 0;
        if (t == 0) { colerr[0] = 0u; colerr[1] = 0u; active[0] = 1; out[0] = 0.f; }
    }
}

// ---------------------------------------------------------------- gemm ------
// Exact 3-way bf16 truncation split: v = b0 + b1 + b2 (+ r3, |r3|<=2^-27|v|).
static __device__ __forceinline__ void split3(float v, ushort& h0, ushort& h1, ushort& h2)
{
    unsigned u0 = __float_as_uint(v);
    h0 = (ushort)(u0 >> 16);
    float r1 = v - __uint_as_float(u0 & 0xFFFF0000u);
    unsigned u1 = __float_as_uint(r1);
    h1 = (ushort)(u1 >> 16);
    float r2 = r1 - __uint_as_float(u1 & 0xFFFF0000u);
    h2 = (ushort)(__float_as_uint(r2) >> 16);
}

// Block tile 128i x 128j, K-chunks of 32, grid (256 jb, 2 ib) = 512 blocks.
// Frag layouts (m89/m91-verified); y is [j][k] row-major = B^T identical frag.
// R15: stores go to the TILED G layout (tile = 2*blockIdx.x + (nj>>2)).
__global__ __launch_bounds__(256, 1) void gemm_k(
    const float* __restrict__ x, const float* __restrict__ y, float* __restrict__ G)
{
    __shared__ __align__(16) ushort xs0[5120], xs1[5120], xs2[5120];
    __shared__ __align__(16) ushort ys0[5120], ys1[5120], ys2[5120];

    const int t   = threadIdx.x;
    const int jb  = blockIdx.x << 7;   // 128-col slab
    const int ib  = blockIdx.y << 7;   // 128-row slab
    const int w   = t >> 6;            // wave 0..3
    const int ln  = t & 63;
    const int q   = ln >> 4;           // quad 0..3
    const int l15 = ln & 15;

    const float4* x4 = (const float4*)x;
    const float4* y4 = (const float4*)y;

    f32x4 acc[2][8];
#pragma unroll
    for (int mi = 0; mi < 2; ++mi)
#pragma unroll
        for (int nj = 0; nj < 8; ++nj) acc[mi][nj] = (f32x4){0.f, 0.f, 0.f, 0.f};

    for (int kc = 0; kc < 12; ++kc) {
        __syncthreads();
#pragma unroll
        for (int p = 0; p < 4; ++p) {
            const int f  = (t << 2) + p;       // 0..1023 float4 slots
            const int r  = f >> 3, c4 = f & 7; // row, k-quad
            const int o  = r * 40 + (c4 << 2);
            float4 vx = x4[(ib + r) * 96 + (kc << 3) + c4];
            ushort a0,a1,a2,b0,b1,b2,c0,c1,c2,d0,d1,d2;
            split3(vx.x, a0,a1,a2); split3(vx.y, b0,b1,b2);
            split3(vx.z, c0,c1,c2); split3(vx.w, d0,d1,d2);
            *(ushort4*)&xs0[o] = make_ushort4(a0,b0,c0,d0);
            *(ushort4*)&xs1[o] = make_ushort4(a1,b1,c1,d1);
            *(ushort4*)&xs2[o] = make_ushort4(a2,b2,c2,d2);
            float4 vy = y4[(jb + r) * 96 + (kc << 3) + c4];
            split3(vy.x, a0,a1,a2); split3(vy.y, b0,b1,b2);
            split3(vy.z, c0,c1,c2); split3(vy.w, d0,d1,d2);
            *(ushort4*)&ys0[o] = make_ushort4(a0,b0,c0,d0);
            *(ushort4*)&ys1[o] = make_ushort4(a1,b1,c1,d1);
            *(ushort4*)&ys2[o] = make_ushort4(a2,b2,c2,d2);
        }
        __syncthreads();

        bf16x8 A[3][2];
#pragma unroll
        for (int mi = 0; mi < 2; ++mi) {
            const int off = ((w << 5) + (mi << 4) + l15) * 40 + (q << 3);
            A[0][mi] = *(const bf16x8*)&xs0[off];
            A[1][mi] = *(const bf16x8*)&xs1[off];
            A[2][mi] = *(const bf16x8*)&xs2[off];
        }
#pragma unroll
        for (int nj = 0; nj < 8; ++nj) {
            const int off = ((nj << 4) + l15) * 40 + (q << 3);
            bf16x8 B0 = *(const bf16x8*)&ys0[off];
            bf16x8 B1 = *(const bf16x8*)&ys1[off];
            bf16x8 B2 = *(const bf16x8*)&ys2[off];
#pragma unroll
            for (int mi = 0; mi < 2; ++mi) {
                f32x4 c = acc[mi][nj];
                c = __builtin_amdgcn_mfma_f32_16x16x32_bf16(A[0][mi], B0, c, 0, 0, 0);
                c = __builtin_amdgcn_mfma_f32_16x16x32_bf16(A[0][mi], B1, c, 0, 0, 0);
                c = __builtin_amdgcn_mfma_f32_16x16x32_bf16(A[1][mi], B0, c, 0, 0, 0);
                c = __builtin_amdgcn_mfma_f32_16x16x32_bf16(A[1][mi], B1, c, 0, 0, 0);
                c = __builtin_amdgcn_mfma_f32_16x16x32_bf16(A[0][mi], B2, c, 0, 0, 0);
                c = __builtin_amdgcn_mfma_f32_16x16x32_bf16(A[2][mi], B0, c, 0, 0, 0);
                acc[mi][nj] = c;
            }
        }
    }
    // Tiled store: element (gi, gj) -> G[(gj>>6)*16384 + gi*64 + (gj&63)]
#pragma unroll
    for (int mi = 0; mi < 2; ++mi) {
        const int gi0 = ib + (w << 5) + (mi << 4) + (q << 2);
#pragma unroll
        for (int nj = 0; nj < 8; ++nj) {
            const int tidx = (blockIdx.x << 1) + (nj >> 2);
            const int cc   = ((nj & 3) << 4) + l15;
            float* base = &G[(size_t)tidx * 16384 + gi0 * 64 + cc];
#pragma unroll
            for (int r = 0; r < 4; ++r)
                base[r * 64] = 40.f * acc[mi][nj][r];
        }
    }
}

// -------------------------------------------- iteration 1 (log-safe) --------
// R11 structure (sink_fast-shaped exact lse); R15: block b reads TILE b =
// contiguous 64KB (each wave-load = 1KB contiguous).
//   1) colmax M_j over (G+su)   2) colexpsum -> W_j
//   3) rowmax R_i over (G+W)    4) rowexpsum; cross-block lse combine.
__global__ __launch_bounds__(256, 2) void sink_step2(
    const float* __restrict__ G, float* __restrict__ su,
    float* __restrict__ W, float2* __restrict__ pms, float2* __restrict__ lms,
    int* __restrict__ cnt)
{
    __shared__ float su_lds[256];
    __shared__ float comb[1024];
    __shared__ float Mlds[64];
    __shared__ float Wlds[64];
    __shared__ float Rlds[256];
    __shared__ float r_arr[256 * 17];
    __shared__ int lastf;

    const int t  = threadIdx.x;
    const int b  = blockIdx.x;
    const int j0 = b << 6;
    const int jq = t & 15;
    const int is = t >> 4;

    su_lds[t] = su[t];
    __syncthreads();

    const float4* G4 = (const float4*)G;
    float4 tile[16];
#pragma unroll
    for (int k = 0; k < 16; ++k) {
        int i = is + (k << 4);
        tile[k] = G4[(b << 12) + (i << 4) + jq];
    }
#pragma unroll
    for (int k = 0; k < 16; ++k) PIN4(tile[k]);

    // ---- pass 1: column max of (G+su) over i ----
    float m0 = -INFINITY, m1 = -INFINITY, m2 = -INFINITY, m3 = -INFINITY;
#pragma unroll
    for (int k = 0; k < 16; ++k) {
        float sk = su_lds[is + (k << 4)];
        m0 = fmaxf(m0, tile[k].x + sk);
        m1 = fmaxf(m1, tile[k].y + sk);
        m2 = fmaxf(m2, tile[k].z + sk);
        m3 = fmaxf(m3, tile[k].w + sk);
    }
    ((float4*)comb)[(is << 4) + jq] = make_float4(m0, m1, m2, m3);
    __syncthreads();
    if (t < 64) {
        float m = -INFINITY;
#pragma unroll
        for (int s = 0; s < 16; ++s) m = fmaxf(m, comb[(s << 6) + t]);
        Mlds[t] = m;
    }
    __syncthreads();
    float4 Mq = make_float4(Mlds[4 * jq + 0], Mlds[4 * jq + 1],
                            Mlds[4 * jq + 2], Mlds[4 * jq + 3]);

    // ---- pass 2: column expsum -> W_j ----
    float s0 = 0.f, s1 = 0.f, s2 = 0.f, s3 = 0.f;
#pragma unroll
    for (int k = 0; k < 16; ++k) {
        float sk = su_lds[is + (k << 4)];
        s0 += __expf(tile[k].x + sk - Mq.x);
        s1 += __expf(tile[k].y + sk - Mq.y);
        s2 += __expf(tile[k].z + sk - Mq.z);
        s3 += __expf(tile[k].w + sk - Mq.w);
    }
    ((float4*)comb)[(is << 4) + jq] = make_float4(s0, s1, s2, s3);
    __syncthreads();
    if (t < 64) {
        float ssum = 0.f;
#pragma unroll
        for (int s = 0; s < 16; ++s) ssum += comb[(s << 6) + t];
        float Wj = LOG_B - (Mlds[t] + __logf(ssum));
        Wlds[t] = Wj;
        W[j0 + t] = Wj;
    }
    __syncthreads();
    float4 Wq = make_float4(Wlds[4 * jq + 0], Wlds[4 * jq + 1],
                            Wlds[4 * jq + 2], Wlds[4 * jq + 3]);

    // ---- pass 3: row max of (G+W) over this block's 64 j ----
#pragma unroll
    for (int k = 0; k < 16; ++k) {
        float a0 = tile[k].x + Wq.x;
        float a1 = tile[k].y + Wq.y;
        float a2 = tile[k].z + Wq.z;
        float a3 = tile[k].w + Wq.w;
        r_arr[(is + (k << 4)) * 17 + jq] = fmaxf(fmaxf(a0, a1), fmaxf(a2, a3));
    }
    __syncthreads();
    {
        float R = -INFINITY;
#pragma unroll
        for (int p = 0; p < 16; ++p) R = fmaxf(R, r_arr[t * 17 + p]);
        Rlds[t] = R;
    }
    __syncthreads();

    // ---- pass 4: row expsum vs R ----
#pragma unroll
    for (int k = 0; k < 16; ++k) {
        float Rr = Rlds[is + (k << 4)];
        float s = __expf(tile[k].x + Wq.x - Rr) + __expf(tile[k].y + Wq.y - Rr) +
                  __expf(tile[k].z + Wq.z - Rr) + __expf(tile[k].w + Wq.w - Rr);
        r_arr[(is + (k << 4)) * 17 + jq] = s;
    }
    __syncthreads();
    {
        float s = 0.f;
#pragma unroll
        for (int p = 0; p < 16; ++p) s += r_arr[t * 17 + p];
        pms[(b << 8) + t] = make_float2(Rlds[t], s);
    }

    // ---- two-level cross-block lse combine ----
    __threadfence();
    if (t == 0) lastf = (atomicAdd(cnt + (b >> 4), 1) == 15);
    __syncthreads();
    if (!lastf) return;
    __threadfence();

    const int g = b >> 4;
    {
        float cm[4] = {-INFINITY, -INFINITY, -INFINITY, -INFINITY};
        float cs[4] = {0.f, 0.f, 0.f, 0.f};
#pragma unroll
        for (int p = 0; p < 16; p += 4) {
#pragma unroll
            for (int c = 0; c < 4; ++c) {
                float2 v = pms[(((g << 4) + p + c) << 8) + t];
                float nm = fmaxf(cm[c], v.x);
                cs[c] = cs[c] * __expf(cm[c] - nm) + v.y * __expf(v.x - nm);
                cm[c] = nm;
            }
        }
        float m = cm[0], s = cs[0];
#pragma unroll
        for (int c = 1; c < 4; ++c) {
            float nm = fmaxf(m, cm[c]);
            s = s * __expf(m - nm) + cs[c] * __expf(cm[c] - nm);
            m = nm;
        }
        lms[(g << 8) + t] = make_float2(m, s);
    }

    __threadfence();
    if (t == 0) lastf = (atomicAdd(cnt + 32, 1) == 31);
    __syncthreads();
    if (!lastf) return;
    __threadfence();

    {
        float cm[4] = {-INFINITY, -INFINITY, -INFINITY, -INFINITY};
        float cs[4] = {0.f, 0.f, 0.f, 0.f};
#pragma unroll
        for (int p = 0; p < 32; p += 4) {
#pragma unroll
            for (int c = 0; c < 4; ++c) {
                float2 v = lms[((p + c) << 8) + t];
                float nm = fmaxf(cm[c], v.x);
                cs[c] = cs[c] * __expf(cm[c] - nm) + v.y * __expf(v.x - nm);
                cm[c] = nm;
            }
        }
        float m = cm[0], s = cs[0];
#pragma unroll
        for (int c = 1; c < 4; ++c) {
            float nm = fmaxf(m, cm[c]);
            s = s * __expf(m - nm) + cs[c] * __expf(cm[c] - nm);
            m = nm;
        }
        su[t] = LOG_A - (m + __logf(s));
    }
}

// -------------------------------------------- iteration (fast, 2..100) ------
// E-reuse: tile := exp((G+su) - M_j) after the column pass; phase R is one
// fma/elem vs 1/S_j; cross-block combine = plain sums (row sums >= a*b).
// R15: block b reads tile b contiguously.
__global__ __launch_bounds__(256, 2) void sink_fast(
    const float* __restrict__ G, float* __restrict__ su,
    float* __restrict__ W, float* __restrict__ prow, float* __restrict__ lrow,
    int* __restrict__ cnt, const int* __restrict__ active)
{
    if (active[0] == 0) return;
    __shared__ float su_lds[256];
    __shared__ float comb[1024];
    __shared__ float Mlds[64];
    __shared__ float ecol[64];
    __shared__ float s_arr[256 * 17];
    __shared__ int lastf;

    const int t  = threadIdx.x;
    const int b  = blockIdx.x;
    const int j0 = b << 6;
    const int jq = t & 15;
    const int is = t >> 4;

    su_lds[t] = su[t];
    __syncthreads();

    const float4* G4 = (const float4*)G;
    float4 tile[16];
#pragma unroll
    for (int k = 0; k < 16; ++k) {
        int i = is + (k << 4);
        float4 g = G4[(b << 12) + (i << 4) + jq];
        float s = su_lds[i];
        tile[k] = make_float4(g.x + s, g.y + s, g.z + s, g.w + s);
    }
#pragma unroll
    for (int k = 0; k < 16; ++k) PIN4(tile[k]);

    // column max over i
    float m0 = -INFINITY, m1 = -INFINITY, m2 = -INFINITY, m3 = -INFINITY;
#pragma unroll
    for (int k = 0; k < 16; ++k) {
        m0 = fmaxf(m0, tile[k].x);
        m1 = fmaxf(m1, tile[k].y);
        m2 = fmaxf(m2, tile[k].z);
        m3 = fmaxf(m3, tile[k].w);
    }
    ((float4*)comb)[(is << 4) + jq] = make_float4(m0, m1, m2, m3);
    __syncthreads();
    if (t < 64) {
        float m = -INFINITY;
#pragma unroll
        for (int s = 0; s < 16; ++s) m = fmaxf(m, comb[(s << 6) + t]);
        Mlds[t] = m;
    }
    __syncthreads();
    float4 Mq = make_float4(Mlds[4 * jq + 0], Mlds[4 * jq + 1],
                            Mlds[4 * jq + 2], Mlds[4 * jq + 3]);

    // E = exp(tile - M), column sums S
    float s0 = 0.f, s1 = 0.f, s2 = 0.f, s3 = 0.f;
#pragma unroll
    for (int k = 0; k < 16; ++k) {
        tile[k].x = __expf(tile[k].x - Mq.x); s0 += tile[k].x;
        tile[k].y = __expf(tile[k].y - Mq.y); s1 += tile[k].y;
        tile[k].z = __expf(tile[k].z - Mq.z); s2 += tile[k].z;
        tile[k].w = __expf(tile[k].w - Mq.w); s3 += tile[k].w;
    }
    ((float4*)comb)[(is << 4) + jq] = make_float4(s0, s1, s2, s3);
    __syncthreads();
    if (t < 64) {
        float ssum = 0.f;
#pragma unroll
        for (int s = 0; s < 16; ++s) ssum += comb[(s << 6) + t];
        W[j0 + t] = LOG_B - (Mlds[t] + __logf(ssum));
        ecol[t]   = 1.0f / ssum;            // = exp(W+M)/b
    }
    __syncthreads();
    float4 Eq = make_float4(ecol[4 * jq + 0], ecol[4 * jq + 1],
                            ecol[4 * jq + 2], ecol[4 * jq + 3]);

    // phase R: row partial = dot(E_rowslice, 1/S)
#pragma unroll
    for (int k = 0; k < 16; ++k) {
        float r = tile[k].x * Eq.x + tile[k].y * Eq.y +
                  tile[k].z * Eq.z + tile[k].w * Eq.w;
        s_arr[(is + (k << 4)) * 17 + jq] = r;
    }
    __syncthreads();
    {
        float s = 0.f;
#pragma unroll
        for (int p = 0; p < 16; ++p) s += s_arr[t * 17 + p];
        prow[(b << 8) + t] = s;
    }

    // two-level plain-sum combine
    __threadfence();
    if (t == 0) lastf = (atomicAdd(cnt + (b >> 4), 1) == 15);
    __syncthreads();
    if (!lastf) return;
    __threadfence();

    const int g = b >> 4;
    {
        float acc = 0.f;
#pragma unroll
        for (int p = 0; p < 16; ++p) acc += prow[(((g << 4) + p) << 8) + t];
        lrow[(g << 8) + t] = acc;
    }
    __threadfence();
    if (t == 0) lastf = (atomicAdd(cnt + 32, 1) == 31);
    __syncthreads();
    if (!lastf) return;
    __threadfence();
    {
        float tot = 0.f;
#pragma unroll
        for (int p = 0; p < 32; ++p) tot += lrow[(p << 8) + t];
        su[t] = (LOG_A - LOG_B) + su_lds[t] - __logf(tot);
    }
}

// --------------------------------------------- absorb-step column error -----
__global__ __launch_bounds__(256, 2) void sink_colerr(
    const float* __restrict__ G, const float* __restrict__ su,
    const float* __restrict__ W, unsigned* __restrict__ colerr, int slot,
    int* __restrict__ counter, int* __restrict__ active, int gated)
{
    if (gated && active[0] == 0) return;
    __shared__ float su_lds[256];
    __shared__ float comb[1024];
    __shared__ float Mlds[64];

    const int t  = threadIdx.x;
    const int b  = blockIdx.x;
    const int j0 = b << 6;
    const int jq = t & 15;
    const int is = t >> 4;

    su_lds[t] = su[t];
    __syncthreads();

    const float4* G4 = (const float4*)G;
    float4 tile[16];
#pragma unroll
    for (int k = 0; k < 16; ++k) {
        int i = is + (k << 4);
        tile[k] = G4[(b << 12) + (i << 4) + jq];
    }
#pragma unroll
    for (int k = 0; k < 16; ++k) PIN4(tile[k]);

    float m0 = -INFINITY, m1 = -INFINITY, m2 = -INFINITY, m3 = -INFINITY;
#pragma unroll
    for (int k = 0; k < 16; ++k) {
        float sk = su_lds[is + (k << 4)];
        m0 = fmaxf(m0, tile[k].x + sk);
        m1 = fmaxf(m1, tile[k].y + sk);
        m2 = fmaxf(m2, tile[k].z + sk);
        m3 = fmaxf(m3, tile[k].w + sk);
    }
    ((float4*)comb)[(is << 4) + jq] = make_float4(m0, m1, m2, m3);
    __syncthreads();
    if (t < 64) {
        float m = -INFINITY;
#pragma unroll
        for (int s = 0; s < 16; ++s) m = fmaxf(m, comb[(s << 6) + t]);
        Mlds[t] = m;
    }
    __syncthreads();
    float4 Mq = make_float4(Mlds[4 * jq + 0], Mlds[4 * jq + 1],
                            Mlds[4 * jq + 2], Mlds[4 * jq + 3]);
    float s0 = 0.f, s1 = 0.f, s2 = 0.f, s3 = 0.f;
#pragma unroll
    for (int k = 0; k < 16; ++k) {
        float sk = su_lds[is + (k << 4)];
        s0 += __expf(tile[k].x + sk - Mq.x);
        s1 += __expf(tile[k].y + sk - Mq.y);
        s2 += __expf(tile[k].z + sk - Mq.z);
        s3 += __expf(tile[k].w + sk - Mq.w);
    }
    ((float4*)comb)[(is << 4) + jq] = make_float4(s0, s1, s2, s3);
    __syncthreads();
    if (t < 64) {
        float ssum = 0.f;
#pragma unroll
        for (int s = 0; s < 16; ++s) ssum += comb[(s << 6) + t];
        float Aj  = Mlds[t] + __logf(ssum);
        float col = __expf(Aj + W[j0 + t]);
        float d   = fabsf(col - BVAL);
        for (int off = 32; off; off >>= 1) d = fmaxf(d, __shfl_down(d, off));
        if (t == 0) {
            atomicMax(colerr + slot, __float_as_uint(d));
            __threadfence();
            if (atomicAdd(counter, 1) == 511) {
                __threadfence();
                unsigned e = atomicMax(colerr + slot, 0u);
                active[0] = (__uint_as_float(e) > 0.005f) ? 1 : 0;
            }
        }
    }
}

// ------------------------------------------------------------- finalize -----
// Block b owns cols [128b,128b+128) = tiles 2b, 2b+1 (contiguous reads).
// transp writes to OUT stay row-major (output layout) and nontemporal.
__global__ __launch_bounds__(256) void finalize_k(
    const float* __restrict__ G, const float* __restrict__ su,
    const float* __restrict__ W, const float* __restrict__ nx,
    const float* __restrict__ ny, float* __restrict__ out)
{
    __shared__ float su_lds[256], nx_lds[256];
    __shared__ float red[4];
    const int t = threadIdx.x, b = blockIdx.x;
    const int j0 = b << 7;
    const int jq = t & 31;
    const int ig = t >> 5;
    su_lds[t] = su[t];
    nx_lds[t] = nx[t];
    __syncthreads();

    const float4* G4 = (const float4*)G;
    const float4 Wq  = ((const float4*)W)[(j0 >> 2) + jq];
    const float4 nyq = ((const float4*)ny)[(j0 >> 2) + jq];
    const int tidx = (b << 1) + (jq >> 4);     // tile for cols 128b + 4*jq
    const int cq   = jq & 15;                  // float4-slot within tile
    const int jbase = 1 + j0 + (jq << 2);
    float acc = 0.f;
#pragma unroll 4
    for (int it = 0; it < 32; ++it) {
        const int i = ig + (it << 3);
        float4 g = G4[(tidx << 12) + (i << 4) + cq];
        const float si = su_lds[i], nxi = nx_lds[i];
        float v0 = __expf(g.x + si + Wq.x);
        float v1 = __expf(g.y + si + Wq.y);
        float v2 = __expf(g.z + si + Wq.z);
        float v3 = __expf(g.w + si + Wq.w);
        float* o = out + jbase + (size_t)i * 32768;
        __builtin_nontemporal_store(v0, o + 0);
        __builtin_nontemporal_store(v1, o + 1);
        __builtin_nontemporal_store(v2, o + 2);
        __builtin_nontemporal_store(v3, o + 3);
        acc += v0 * (nxi + nyq.x - 0.05f * g.x) +
               v1 * (nxi + nyq.y - 0.05f * g.y) +
               v2 * (nxi + nyq.z - 0.05f * g.z) +
               v3 * (nxi + nyq.w - 0.05f * g.w);
    }
    for (int off = 32; off; off >>= 1) acc += __shfl_down(acc, off);
    if ((t & 63) == 0) red[t >> 6] = acc;
    __syncthreads();
    if (t == 0) atomicAdd(out, red[0] + red[1] + red[2] + red[3]);
}

// ---------------------------------------------------------------- host ------
extern "C" void kernel_launch(void* const* d_in, const int* in_sizes, int n_in,
                              void* d_out, int out_size, void* d_ws, size_t ws_size,
                              hipStream_t stream)
{
    const float* x = (const float*)d_in[0];   // [256, 384]
    const float* y = (const float*)d_in[1];   // [32768, 384]
    float* out = (float*)d_out;               // [1 + 256*32768]

    float* ws   = (float*)d_ws;
    float* G    = ws;                 // 8388608 (tiled: [512][256][64])
    float* Wv   = G + 8388608;        // 32768
    float* su   = Wv + 32768;         // 256
    float* nx   = su + 256;           // 256
    float* ny   = nx + 256;           // 32768
    float2* pms = (float2*)(ny + 32768);           // 131072 float2 (iter 1)
    float2* lms = pms + 131072;                    // 8192 float2
    float* prow = (float*)(lms + 8192);            // 131072 (iters 2+)
    float* lrow = prow + 131072;                   // 8192
    unsigned* colerr = (unsigned*)(lrow + 8192);   // 2
    int* active   = (int*)(colerr + 2);            // 1
    int* counters = active + 1;                    // 4096

    init_k<<<8257, 256, 0, stream>>>(x, y, nx, ny, su, colerr, active, counters, out);
    gemm_k<<<dim3(256, 2), 256, 0, stream>>>(x, y, G);

    // iteration 1 (log-safe, tiled-contiguous) + absorb error check
    sink_step2<<<512, 256, 0, stream>>>(G, su, Wv, pms, lms, counters + 0);
    sink_colerr<<<512, 256, 0, stream>>>(G, su, Wv, colerr, 0, counters + 4000, active, 0);

    for (int tt = 2; tt <= 100; ++tt) {
        sink_fast<<<512, 256, 0, stream>>>(G, su, Wv, prow, lrow,
                                           counters + 40 * (tt - 1), active);
        if (tt == 51)   // absorb at cpt_n=51: error check gates the rest
            sink_colerr<<<512, 256, 0, stream>>>(G, su, Wv, colerr, 1,
                                                 counters + 4001, active, 1);
    }

    finalize_k<<<256, 256, 0, stream>>>(G, su, Wv, nx, ny, out);
}

// Round 8
// 308.225 us; speedup vs baseline: 1.2840x; 1.2431x over previous
//
#include <hip/hip_runtime.h>
#include <math.h>

// ---------------------------------------------------------------------------
// Sinkhorn ETP (FASTopic) on MI355X.
// n=256 topics, m=32768 words, D=384.
//
//   log_K0[i,j] = G[i,j] + su0[i] + sv0[j],  G = 40 * x@y^T
//   Per iteration:  W[j] = log_b - lse_i(G+su);  su'[i] = log_a - lse_j(G+W)
//   Final: transp[i,j] = exp(G+su[i]+W[j]); M = nx[i]+ny[j]-0.05*G;
//          loss = sum(transp*M)
//
// R9-R15 (mechanism hunt, all falsified as levers): the first-after-gemm G
// reader pays ~76us (17MB @ 240GB/s) regardless of its code, VGPRs, reg
// pinning, LDS, nt stores, XCD swizzle, or even a fully-contiguous tiled
// layout (R15: 64KB sequential per block - FETCH/dur identical). The cost is
// a property of the gemm->reader BOUNDARY (drain/visibility of 32MB fresh
// writes through non-coherent L2s), not of the reader. Unremovable by reader
// rewrites; paid exactly once.
//
// R16 (step back - attack the 240us everyone ignored): ONE persistent kernel
// replaces the 101-launch iteration chain. 256 blocks (1/CU, conservative
// co-residency), block b holds G-tile b (256 rows x 128 cols, layout
// [256][256][128]) in 128 pinned VGPRs for the whole run. Column lse = fully
// block-local (block owns all rows of its cols -> W never crosses blocks).
// Row reduction via prow + device-scope generation barrier (arrival counter,
// last block computes su, atomicExch release; spin via atomicCAS(gen,-1,-1)
// device-scope read). Convergence checks (after iter 1 / iter 51) fused;
// break on converge -> 49 dead launches + 2 colerr launches eliminated.
// G read from memory ONCE (the 76us stays, inside the load); iterations run
// on regs/LDS + ~0.3MB/iter combine traffic. W kept in LDS, written at exit.
// Predicted: 4 dispatches; sink_loop 190-240us; total ~250-310us.
// Falsifier: hang -> barrier bug (revert); unchanged -> fuse gemm in next.
// ---------------------------------------------------------------------------

#define N_TOPIC 256
#define N_WORD  32768

static constexpr float LOG_A = -5.545177444479562f;    // log(1/256 + 1e-30)
static constexpr float LOG_B = -10.397207708399179f;   // log(1/32768 + 1e-30)
static constexpr float BVAL  = 3.0517578125e-05f;      // 1/32768

typedef float f32x4 __attribute__((ext_vector_type(4)));
typedef short bf16x8 __attribute__((ext_vector_type(8)));

// Keep a float4's lanes pinned in VGPRs (opaque use+def; no remat).
#define PIN4(v) asm volatile("" : "+v"((v).x), "+v"((v).y), "+v"((v).z), "+v"((v).w))

// ---------------------------------------------------------------- init ------
__global__ __launch_bounds__(256) void init_k(
    const float* __restrict__ x, const float* __restrict__ y,
    float* __restrict__ nx, float* __restrict__ ny, float* __restrict__ su,
    unsigned* __restrict__ colerr, int* __restrict__ active,
    int* __restrict__ counters, float* __restrict__ out)
{
    const int b = blockIdx.x, t = threadIdx.x;
    const int w = t >> 6, l = t & 63;
    if (b < 8192) {                       // ||y_j||^2, 4 rows/block (wave per row)
        const int r = (b << 2) + w;
        const float4* y4 = (const float4*)y;
        float4 v = y4[r * 96 + l];
        float s = v.x * v.x + v.y * v.y + v.z * v.z + v.w * v.w;
        if (l < 32) {
            float4 u = y4[r * 96 + 64 + l];
            s += u.x * u.x + u.y * u.y + u.z * u.z + u.w * u.w;
        }
        for (int off = 32; off; off >>= 1) s += __shfl_down(s, off);
        if (l == 0) ny[r] = s;
    } else if (b < 8256) {                // ||x_i||^2 and su0 = -20*nx
        const int r = ((b - 8192) << 2) + w;
        const float4* x4 = (const float4*)x;
        float4 v = x4[r * 96 + l];
        float s = v.x * v.x + v.y * v.y + v.z * v.z + v.w * v.w;
        if (l < 32) {
            float4 u = x4[r * 96 + 64 + l];
            s += u.x * u.x + u.y * u.y + u.z * u.z + u.w * u.w;
        }
        for (int off = 32; off; off >>= 1) s += __shfl_down(s, off);
        if (l == 0) { nx[r] = s; su[r] = -20.f * s; }
    } else {
        for (int k = t; k < 4096; k += 256) counters[k] = 0;
        if (t == 0) { colerr[0] = 0u; colerr[1] = 0u; active[0] = 1; out[0] = 0.f; }
    }
}

// ---------------------------------------------------------------- gemm ------
// Exact 3-way bf16 truncation split: v = b0 + b1 + b2 (+ r3, |r3|<=2^-27|v|).
static __device__ __forceinline__ void split3(float v, ushort& h0, ushort& h1, ushort& h2)
{
    unsigned u0 = __float_as_uint(v);
    h0 = (ushort)(u0 >> 16);
    float r1 = v - __uint_as_float(u0 & 0xFFFF0000u);
    unsigned u1 = __float_as_uint(r1);
    h1 = (ushort)(u1 >> 16);
    float r2 = r1 - __uint_as_float(u1 & 0xFFFF0000u);
    h2 = (ushort)(__float_as_uint(r2) >> 16);
}

// Block tile 128i x 128j, K-chunks of 32, grid (256 jb, 2 ib) = 512 blocks.
// R16: stores go to tile layout [tile=j/128][i][j%128]: block jb owns tile jb.
__global__ __launch_bounds__(256, 1) void gemm_k(
    const float* __restrict__ x, const float* __restrict__ y, float* __restrict__ G)
{
    __shared__ __align__(16) ushort xs0[5120], xs1[5120], xs2[5120];
    __shared__ __align__(16) ushort ys0[5120], ys1[5120], ys2[5120];

    const int t   = threadIdx.x;
    const int jb  = blockIdx.x << 7;   // 128-col slab
    const int ib  = blockIdx.y << 7;   // 128-row slab
    const int w   = t >> 6;            // wave 0..3
    const int ln  = t & 63;
    const int q   = ln >> 4;           // quad 0..3
    const int l15 = ln & 15;

    const float4* x4 = (const float4*)x;
    const float4* y4 = (const float4*)y;

    f32x4 acc[2][8];
#pragma unroll
    for (int mi = 0; mi < 2; ++mi)
#pragma unroll
        for (int nj = 0; nj < 8; ++nj) acc[mi][nj] = (f32x4){0.f, 0.f, 0.f, 0.f};

    for (int kc = 0; kc < 12; ++kc) {
        __syncthreads();
#pragma unroll
        for (int p = 0; p < 4; ++p) {
            const int f  = (t << 2) + p;       // 0..1023 float4 slots
            const int r  = f >> 3, c4 = f & 7; // row, k-quad
            const int o  = r * 40 + (c4 << 2);
            float4 vx = x4[(ib + r) * 96 + (kc << 3) + c4];
            ushort a0,a1,a2,b0,b1,b2,c0,c1,c2,d0,d1,d2;
            split3(vx.x, a0,a1,a2); split3(vx.y, b0,b1,b2);
            split3(vx.z, c0,c1,c2); split3(vx.w, d0,d1,d2);
            *(ushort4*)&xs0[o] = make_ushort4(a0,b0,c0,d0);
            *(ushort4*)&xs1[o] = make_ushort4(a1,b1,c1,d1);
            *(ushort4*)&xs2[o] = make_ushort4(a2,b2,c2,d2);
            float4 vy = y4[(jb + r) * 96 + (kc << 3) + c4];
            split3(vy.x, a0,a1,a2); split3(vy.y, b0,b1,b2);
            split3(vy.z, c0,c1,c2); split3(vy.w, d0,d1,d2);
            *(ushort4*)&ys0[o] = make_ushort4(a0,b0,c0,d0);
            *(ushort4*)&ys1[o] = make_ushort4(a1,b1,c1,d1);
            *(ushort4*)&ys2[o] = make_ushort4(a2,b2,c2,d2);
        }
        __syncthreads();

        bf16x8 A[3][2];
#pragma unroll
        for (int mi = 0; mi < 2; ++mi) {
            const int off = ((w << 5) + (mi << 4) + l15) * 40 + (q << 3);
            A[0][mi] = *(const bf16x8*)&xs0[off];
            A[1][mi] = *(const bf16x8*)&xs1[off];
            A[2][mi] = *(const bf16x8*)&xs2[off];
        }
#pragma unroll
        for (int nj = 0; nj < 8; ++nj) {
            const int off = ((nj << 4) + l15) * 40 + (q << 3);
            bf16x8 B0 = *(const bf16x8*)&ys0[off];
            bf16x8 B1 = *(const bf16x8*)&ys1[off];
            bf16x8 B2 = *(const bf16x8*)&ys2[off];
#pragma unroll
            for (int mi = 0; mi < 2; ++mi) {
                f32x4 c = acc[mi][nj];
                c = __builtin_amdgcn_mfma_f32_16x16x32_bf16(A[0][mi], B0, c, 0, 0, 0);
                c = __builtin_amdgcn_mfma_f32_16x16x32_bf16(A[0][mi], B1, c, 0, 0, 0);
                c = __builtin_amdgcn_mfma_f32_16x16x32_bf16(A[1][mi], B0, c, 0, 0, 0);
                c = __builtin_amdgcn_mfma_f32_16x16x32_bf16(A[1][mi], B1, c, 0, 0, 0);
                c = __builtin_amdgcn_mfma_f32_16x16x32_bf16(A[0][mi], B2, c, 0, 0, 0);
                c = __builtin_amdgcn_mfma_f32_16x16x32_bf16(A[2][mi], B0, c, 0, 0, 0);
                acc[mi][nj] = c;
            }
        }
    }
    // Tiled store: (gi, gj) -> G[(gj>>7)*32768 + gi*128 + (gj&127)]
#pragma unroll
    for (int mi = 0; mi < 2; ++mi) {
        const int gi0 = ib + (w << 5) + (mi << 4) + (q << 2);
#pragma unroll
        for (int nj = 0; nj < 8; ++nj) {
            float* base = &G[(size_t)blockIdx.x * 32768 + (size_t)gi0 * 128
                             + (nj << 4) + l15];
#pragma unroll
            for (int r = 0; r < 4; ++r)
                base[r * 128] = 40.f * acc[mi][nj][r];
        }
    }
}

// ----------------------------------------------- persistent barrier ---------
static __device__ __forceinline__ bool bar_arrive(int* cnt, int ph, int t, int* lastf)
{
    __threadfence();
    if (t == 0) *lastf = (atomicAdd(&cnt[ph], 1) == 255);
    __syncthreads();
    return *lastf != 0;
}
static __device__ __forceinline__ void bar_release(int* gen, int ph, int t)
{
    __threadfence();
    if (t == 0) atomicExch(gen, ph);
}
static __device__ __forceinline__ void bar_wait(int* gen, int ph, int t)
{
    if (t == 0) {
        while (atomicCAS(gen, -1, -1) < ph) __builtin_amdgcn_s_sleep(2);
    }
    __syncthreads();
    __threadfence();
}

// ---------------------------------------- persistent Sinkhorn loop ----------
// 256 blocks x 256 threads, 1 block/CU. Block b owns G-tile b: rows 0..255 x
// cols [128b, 128b+128), register-resident (float4 tile[32], pinned).
// Thread mapping: jq = t&31 (float4-col, cols 4jq..4jq+3), ig = t>>5,
// rows i = ig + 8k for k = 0..31.
__global__ __launch_bounds__(256, 1) void sink_loop(
    const float* __restrict__ G, float* __restrict__ su,
    float* __restrict__ W, float2* __restrict__ pms, float* __restrict__ prow,
    int* __restrict__ cnt, int* __restrict__ gen,
    unsigned* __restrict__ colerr, int* __restrict__ active)
{
    __shared__ float su_lds[256];
    __shared__ float mm[1024];       // [8][128] col partials
    __shared__ float ss[1024];
    __shared__ float Mcol[128];
    __shared__ float Wlds[128];
    __shared__ float ecol[128];
    __shared__ float Rlds[256];
    __shared__ float pq[256 * 33];   // row partials (reused every pass)
    __shared__ float errb[128];
    __shared__ int lastf;

    const int t  = threadIdx.x;
    const int b  = blockIdx.x;
    const int jq = t & 31;
    const int ig = t >> 5;
    const int c0 = jq << 2;
    int ph = 1;

    // ---- load tile (once, ever) ----
    const float4* G4 = (const float4*)G;
    float4 tile[32];
#pragma unroll
    for (int k = 0; k < 32; ++k) {
        const int i = ig + (k << 3);
        tile[k] = G4[((size_t)b << 13) + (i << 5) + jq];
    }
#pragma unroll
    for (int k = 0; k < 32; ++k) PIN4(tile[k]);

    su_lds[t] = su[t];               // su0 = -20*|x|^2
    __syncthreads();

    // ================= iteration 1 (log-safe, exact lse) =================
    // col pass: A_j = lse_i(G+su) via per-thread (m,s) partials + lse merge
    {
        float m0=-INFINITY,m1=-INFINITY,m2=-INFINITY,m3=-INFINITY;
#pragma unroll
        for (int k = 0; k < 32; ++k) {
            const float sk = su_lds[ig + (k << 3)];
            m0=fmaxf(m0,tile[k].x+sk); m1=fmaxf(m1,tile[k].y+sk);
            m2=fmaxf(m2,tile[k].z+sk); m3=fmaxf(m3,tile[k].w+sk);
        }
        float s0=0.f,s1=0.f,s2=0.f,s3=0.f;
#pragma unroll
        for (int k = 0; k < 32; ++k) {
            const float sk = su_lds[ig + (k << 3)];
            s0+=__expf(tile[k].x+sk-m0); s1+=__expf(tile[k].y+sk-m1);
            s2+=__expf(tile[k].z+sk-m2); s3+=__expf(tile[k].w+sk-m3);
        }
        mm[ig*128+c0+0]=m0; ss[ig*128+c0+0]=s0;
        mm[ig*128+c0+1]=m1; ss[ig*128+c0+1]=s1;
        mm[ig*128+c0+2]=m2; ss[ig*128+c0+2]=s2;
        mm[ig*128+c0+3]=m3; ss[ig*128+c0+3]=s3;
        __syncthreads();
        if (t < 128) {
            float m=-INFINITY, s=0.f;
#pragma unroll
            for (int q = 0; q < 8; ++q) {
                float pmv=mm[q*128+t], psv=ss[q*128+t];
                float nm=fmaxf(m,pmv);
                s = s*__expf(m-nm) + psv*__expf(pmv-nm);
                m = nm;
            }
            Wlds[t] = LOG_B - (m + __logf(s));
        }
        __syncthreads();
    }
    // row pass (exact, two sweeps): rowmax then expsum, cross-block lse
    {
#pragma unroll
        for (int k = 0; k < 32; ++k) {
            const int i = ig + (k << 3);
            float a0=tile[k].x+Wlds[c0], a1=tile[k].y+Wlds[c0+1];
            float a2=tile[k].z+Wlds[c0+2], a3=tile[k].w+Wlds[c0+3];
            pq[i*33+jq] = fmaxf(fmaxf(a0,a1), fmaxf(a2,a3));
        }
        __syncthreads();
        {
            float R=-INFINITY;
#pragma unroll
            for (int q = 0; q < 32; ++q) R = fmaxf(R, pq[t*33+q]);
            Rlds[t] = R;
        }
        __syncthreads();
#pragma unroll
        for (int k = 0; k < 32; ++k) {
            const int i = ig + (k << 3);
            const float Rr = Rlds[i];
            float s = __expf(tile[k].x+Wlds[c0]-Rr)   + __expf(tile[k].y+Wlds[c0+1]-Rr)
                    + __expf(tile[k].z+Wlds[c0+2]-Rr) + __expf(tile[k].w+Wlds[c0+3]-Rr);
            pq[i*33+jq] = s;
        }
        __syncthreads();
        {
            float s = 0.f;
#pragma unroll
            for (int q = 0; q < 32; ++q) s += pq[t*33+q];
            pms[(b << 8) + t] = make_float2(Rlds[t], s);
        }
    }
    if (bar_arrive(cnt, ph, t, &lastf)) {
        __threadfence();
        float m=-INFINITY, s=0.f;
        for (int p = 0; p < 256; ++p) {
            float2 v = pms[(p << 8) + t];
            float nm = fmaxf(m, v.x);
            s = s*__expf(m-nm) + v.y*__expf(v.x-nm);
            m = nm;
        }
        su[t] = LOG_A - (m + __logf(s));
        bar_release(gen, ph, t);
    }
    bar_wait(gen, ph, t); ++ph;
    su_lds[t] = su[t];
    __syncthreads();

    // ---- convergence check #1 (ref cpt_n=1): col marginal err vs b ----
    int act;
    {
        float m0=-INFINITY,m1=-INFINITY,m2=-INFINITY,m3=-INFINITY;
#pragma unroll
        for (int k = 0; k < 32; ++k) {
            const float sk = su_lds[ig + (k << 3)];
            m0=fmaxf(m0,tile[k].x+sk); m1=fmaxf(m1,tile[k].y+sk);
            m2=fmaxf(m2,tile[k].z+sk); m3=fmaxf(m3,tile[k].w+sk);
        }
        float s0=0.f,s1=0.f,s2=0.f,s3=0.f;
#pragma unroll
        for (int k = 0; k < 32; ++k) {
            const float sk = su_lds[ig + (k << 3)];
            s0+=__expf(tile[k].x+sk-m0); s1+=__expf(tile[k].y+sk-m1);
            s2+=__expf(tile[k].z+sk-m2); s3+=__expf(tile[k].w+sk-m3);
        }
        mm[ig*128+c0+0]=m0; ss[ig*128+c0+0]=s0;
        mm[ig*128+c0+1]=m1; ss[ig*128+c0+1]=s1;
        mm[ig*128+c0+2]=m2; ss[ig*128+c0+2]=s2;
        mm[ig*128+c0+3]=m3; ss[ig*128+c0+3]=s3;
        __syncthreads();
        float d = 0.f;
        if (t < 128) {
            float m=-INFINITY, s=0.f;
#pragma unroll
            for (int q = 0; q < 8; ++q) {
                float pmv=mm[q*128+t], psv=ss[q*128+t];
                float nm=fmaxf(m,pmv);
                s = s*__expf(m-nm) + psv*__expf(pmv-nm);
                m = nm;
            }
            d = fabsf(__expf((m + __logf(s)) + Wlds[t]) - BVAL);
            errb[t] = d;
        }
        __syncthreads();
        for (int n = 64; n; n >>= 1) {
            if (t < n) errb[t] = fmaxf(errb[t], errb[t + n]);
            __syncthreads();
        }
        if (t == 0) atomicMax(&colerr[0], __float_as_uint(errb[0]));
        if (bar_arrive(cnt, ph, t, &lastf)) {
            if (t == 0) {
                unsigned e = atomicMax(&colerr[0], 0u);
                active[0] = (__uint_as_float(e) > 0.005f) ? 1 : 0;
            }
            bar_release(gen, ph, t);
        }
        bar_wait(gen, ph, t); ++ph;
        act = active[0];
    }

    // ================= fast iterations 2..100 (E-reuse) =================
    if (act) {
#pragma unroll 1
        for (int tt = 2; tt <= 100; ++tt) {
            // col pass: true col max, then E = exp(G+su-M), col sums S
            {
                float m0=-INFINITY,m1=-INFINITY,m2=-INFINITY,m3=-INFINITY;
#pragma unroll
                for (int k = 0; k < 32; ++k) {
                    const float sk = su_lds[ig + (k << 3)];
                    m0=fmaxf(m0,tile[k].x+sk); m1=fmaxf(m1,tile[k].y+sk);
                    m2=fmaxf(m2,tile[k].z+sk); m3=fmaxf(m3,tile[k].w+sk);
                }
                mm[ig*128+c0+0]=m0; mm[ig*128+c0+1]=m1;
                mm[ig*128+c0+2]=m2; mm[ig*128+c0+3]=m3;
                __syncthreads();
                if (t < 128) {
                    float m=-INFINITY;
#pragma unroll
                    for (int q = 0; q < 8; ++q) m = fmaxf(m, mm[q*128+t]);
                    Mcol[t] = m;
                }
                __syncthreads();
            }
            float4 E[32];
            {
                const float Mc0=Mcol[c0], Mc1=Mcol[c0+1], Mc2=Mcol[c0+2], Mc3=Mcol[c0+3];
                float s0=0.f,s1=0.f,s2=0.f,s3=0.f;
#pragma unroll
                for (int k = 0; k < 32; ++k) {
                    const float sk = su_lds[ig + (k << 3)];
                    E[k].x=__expf(tile[k].x+sk-Mc0); s0+=E[k].x;
                    E[k].y=__expf(tile[k].y+sk-Mc1); s1+=E[k].y;
                    E[k].z=__expf(tile[k].z+sk-Mc2); s2+=E[k].z;
                    E[k].w=__expf(tile[k].w+sk-Mc3); s3+=E[k].w;
                }
                ss[ig*128+c0+0]=s0; ss[ig*128+c0+1]=s1;
                ss[ig*128+c0+2]=s2; ss[ig*128+c0+3]=s3;
                __syncthreads();
                if (t < 128) {
                    float ssum = 0.f;
#pragma unroll
                    for (int q = 0; q < 8; ++q) ssum += ss[q*128+t];
                    Wlds[t] = LOG_B - (Mcol[t] + __logf(ssum));
                    ecol[t] = 1.0f / ssum;
                }
                __syncthreads();
            }
            // row pass: partial = dot(E_rowslice, 1/S)
            {
                const float e0=ecol[c0], e1=ecol[c0+1], e2=ecol[c0+2], e3=ecol[c0+3];
#pragma unroll
                for (int k = 0; k < 32; ++k) {
                    const int i = ig + (k << 3);
                    pq[i*33+jq] = E[k].x*e0 + E[k].y*e1 + E[k].z*e2 + E[k].w*e3;
                }
                __syncthreads();
                float s = 0.f;
#pragma unroll
                for (int q = 0; q < 32; ++q) s += pq[t*33+q];
                prow[(b << 8) + t] = s;
            }
            if (bar_arrive(cnt, ph, t, &lastf)) {
                __threadfence();
                float tot = 0.f;
                for (int p = 0; p < 256; ++p) tot += prow[(p << 8) + t];
                su[t] = (LOG_A - LOG_B) + su_lds[t] - __logf(tot);
                bar_release(gen, ph, t);
            }
            bar_wait(gen, ph, t); ++ph;
            su_lds[t] = su[t];
            __syncthreads();

            if (tt == 51) {
                // convergence check #2 (ref cpt_n=51)
                float m0=-INFINITY,m1=-INFINITY,m2=-INFINITY,m3=-INFINITY;
#pragma unroll
                for (int k = 0; k < 32; ++k) {
                    const float sk = su_lds[ig + (k << 3)];
                    m0=fmaxf(m0,tile[k].x+sk); m1=fmaxf(m1,tile[k].y+sk);
                    m2=fmaxf(m2,tile[k].z+sk); m3=fmaxf(m3,tile[k].w+sk);
                }
                float s0=0.f,s1=0.f,s2=0.f,s3=0.f;
#pragma unroll
                for (int k = 0; k < 32; ++k) {
                    const float sk = su_lds[ig + (k << 3)];
                    s0+=__expf(tile[k].x+sk-m0); s1+=__expf(tile[k].y+sk-m1);
                    s2+=__expf(tile[k].z+sk-m2); s3+=__expf(tile[k].w+sk-m3);
                }
                mm[ig*128+c0+0]=m0; ss[ig*128+c0+0]=s0;
                mm[ig*128+c0+1]=m1; ss[ig*128+c0+1]=s1;
                mm[ig*128+c0+2]=m2; ss[ig*128+c0+2]=s2;
                mm[ig*128+c0+3]=m3; ss[ig*128+c0+3]=s3;
                __syncthreads();
                if (t < 128) {
                    float m=-INFINITY, s=0.f;
#pragma unroll
                    for (int q = 0; q < 8; ++q) {
                        float pmv=mm[q*128+t], psv=ss[q*128+t];
                        float nm=fmaxf(m,pmv);
                        s = s*__expf(m-nm) + psv*__expf(pmv-nm);
                        m = nm;
                    }
                    errb[t] = fabsf(__expf((m + __logf(s)) + Wlds[t]) - BVAL);
                }
                __syncthreads();
                for (int n = 64; n; n >>= 1) {
                    if (t < n) errb[t] = fmaxf(errb[t], errb[t + n]);
                    __syncthreads();
                }
                if (t == 0) atomicMax(&colerr[1], __float_as_uint(errb[0]));
                if (bar_arrive(cnt, ph, t, &lastf)) {
                    if (t == 0) {
                        unsigned e = atomicMax(&colerr[1], 0u);
                        active[0] = (__uint_as_float(e) > 0.005f) ? 1 : 0;
                    }
                    bar_release(gen, ph, t);
                }
                bar_wait(gen, ph, t); ++ph;
                if (active[0] == 0) break;
            }
        }
    }

    // ---- export W of the final iteration for finalize ----
    if (t < 128) W[(b << 7) + t] = Wlds[t];
}

// ------------------------------------------------------------- finalize -----
// Block b owns cols [128b,128b+128) = tile b (contiguous reads).
__global__ __launch_bounds__(256) void finalize_k(
    const float* __restrict__ G, const float* __restrict__ su,
    const float* __restrict__ W, const float* __restrict__ nx,
    const float* __restrict__ ny, float* __restrict__ out)
{
    __shared__ float su_lds[256], nx_lds[256];
    __shared__ float red[4];
    const int t = threadIdx.x, b = blockIdx.x;
    const int j0 = b << 7;
    const int jq = t & 31;
    const int ig = t >> 5;
    su_lds[t] = su[t];
    nx_lds[t] = nx[t];
    __syncthreads();

    const float4* G4 = (const float4*)G;
    const float4 Wq  = ((const float4*)W)[(j0 >> 2) + jq];
    const float4 nyq = ((const float4*)ny)[(j0 >> 2) + jq];
    const int jbase = 1 + j0 + (jq << 2);
    float acc = 0.f;
#pragma unroll 4
    for (int it = 0; it < 32; ++it) {
        const int i = ig + (it << 3);
        float4 g = G4[((size_t)b << 13) + (i << 5) + jq];
        const float si = su_lds[i], nxi = nx_lds[i];
        float v0 = __expf(g.x + si + Wq.x);
        float v1 = __expf(g.y + si + Wq.y);
        float v2 = __expf(g.z + si + Wq.z);
        float v3 = __expf(g.w + si + Wq.w);
        float* o = out + jbase + (size_t)i * 32768;
        __builtin_nontemporal_store(v0, o + 0);
        __builtin_nontemporal_store(v1, o + 1);
        __builtin_nontemporal_store(v2, o + 2);
        __builtin_nontemporal_store(v3, o + 3);
        acc += v0 * (nxi + nyq.x - 0.05f * g.x) +
               v1 * (nxi + nyq.y - 0.05f * g.y) +
               v2 * (nxi + nyq.z - 0.05f * g.z) +
               v3 * (nxi + nyq.w - 0.05f * g.w);
    }
    for (int off = 32; off; off >>= 1) acc += __shfl_down(acc, off);
    if ((t & 63) == 0) red[t >> 6] = acc;
    __syncthreads();
    if (t == 0) atomicAdd(out, red[0] + red[1] + red[2] + red[3]);
}

// ---------------------------------------------------------------- host ------
extern "C" void kernel_launch(void* const* d_in, const int* in_sizes, int n_in,
                              void* d_out, int out_size, void* d_ws, size_t ws_size,
                              hipStream_t stream)
{
    const float* x = (const float*)d_in[0];   // [256, 384]
    const float* y = (const float*)d_in[1];   // [32768, 384]
    float* out = (float*)d_out;               // [1 + 256*32768]

    float* ws   = (float*)d_ws;
    float* G    = ws;                 // 8388608 (tiled [256][256][128])
    float* Wv   = G + 8388608;        // 32768
    float* su   = Wv + 32768;         // 256
    float* nx   = su + 256;           // 256
    float* ny   = nx + 256;           // 32768
    float2* pms = (float2*)(ny + 32768);           // 65536 float2 (iter 1)
    float* prow = (float*)(pms + 65536);           // 65536 (fast iters)
    unsigned* colerr = (unsigned*)(prow + 65536);  // 2
    int* active   = (int*)(colerr + 2);            // 1
    int* counters = active + 1;                    // 4096 (barrier slots + gen)
    int* gen      = counters + 3000;

    init_k<<<8257, 256, 0, stream>>>(x, y, nx, ny, su, colerr, active, counters, out);
    gemm_k<<<dim3(256, 2), 256, 0, stream>>>(x, y, G);
    sink_loop<<<256, 256, 0, stream>>>(G, su, Wv, pms, prow,
                                       counters, gen, colerr, active);
    finalize_k<<<256, 256, 0, stream>>>(G, su, Wv, nx, ny, out);
}